// Round 8
// baseline (497.602 us; speedup 1.0000x reference)
//
#include <hip/hip_runtime.h>
#include <math.h>

#define PI_F 3.14159265358979323846f

__constant__ float c_pkva[12] = {
  -0.0144f, 0.0272f, -0.0526f, 0.0972f, -0.193f, 0.63f,
   0.63f, -0.193f, 0.0972f, -0.0526f, 0.0272f, -0.0144f
};

constexpr int ilog2c(int n) { int l = 0; while (n > 1) { n >>= 1; ++l; } return l; }

// Meyer phi lookup table: [0,1024) for N=1024, [1024,1536) N=512,
// [1536,1792) N=256, [1792,1920) N=128. Filled by phi_init_k each launch.
__device__ float g_phi[1920];
// Radix-4 twiddle table: g_tw[Ns+base] = (cos th, sin th), th = 2pi*base/(4Ns).
__device__ float2 g_tw[512];
constexpr int phi_off(int N) {
  return (N == 1024) ? 0 : (N == 512) ? 1024 : (N == 256) ? 1536 : 1792;
}

__device__ __forceinline__ float phi_dev(int k, int n) {
  int kk = (k < n - k) ? k : (n - k);
  float w = 2.0f * PI_F * (float)kk / (float)n;
  float s = (w - PI_F / 3.0f) * (3.0f / PI_F);
  s = fminf(fmaxf(s, 0.0f), 1.0f);
  float s2 = s * s;
  float beta = s2 * s2 * (35.0f - 84.0f * s + 70.0f * s2 - 20.0f * s2 * s);
  return __cosf(0.5f * PI_F * beta);
}

__global__ void phi_init_k() {
  int i = blockIdx.x * 256 + threadIdx.x;
  if (i < 1024)      g_phi[i] = phi_dev(i, 1024);
  else if (i < 1536) g_phi[i] = phi_dev(i - 1024, 512);
  else if (i < 1792) g_phi[i] = phi_dev(i - 1536, 256);
  else if (i < 1920) g_phi[i] = phi_dev(i - 1792, 128);
  else {
    int idx = i - 1920;
    if (idx >= 1 && idx < 512) {
      int l = 31 - __clz(idx);
      int Ns = 1 << l;
      float th = 2.0f * PI_F * (float)(idx - Ns) / (float)(4 * Ns);
      g_tw[idx] = make_float2(cosf(th), sinf(th));
    }
  }
}

__device__ __forceinline__ float2 cmul(float2 a, float2 b) {
  return make_float2(a.x * b.x - a.y * b.y, a.x * b.y + a.y * b.x);
}
__device__ __forceinline__ float2 cadd(float2 a, float2 b) { return make_float2(a.x + b.x, a.y + b.y); }
__device__ __forceinline__ float2 csub(float2 a, float2 b) { return make_float2(a.x - b.x, a.y - b.y); }

// ---------------------------------------------------------------------------
// In-LDS Stockham radix-4 FFT core (unpadded — proven). NT = N/4.
// ---------------------------------------------------------------------------
template <int N>
__device__ __forceinline__ int fft_core4(float2 (*sbuf)[N], float dirsign, int tid, int cur) {
  constexpr int LOG2 = ilog2c(N);
  constexpr int NT = N / 4;
  constexpr bool LEAD2 = (LOG2 & 1);
  if constexpr (LEAD2) {
#pragma unroll
    for (int j = tid; j < N / 2; j += NT) {
      float2 v0 = sbuf[cur][j], v1 = sbuf[cur][j + N / 2];
      float2 e = cadd(v0, v1), o = csub(v0, v1);
      *(float4*)&sbuf[cur ^ 1][2 * j] = make_float4(e.x, e.y, o.x, o.y);
    }
    cur ^= 1;
    __syncthreads();
  }
#pragma unroll
  for (int Ns = LEAD2 ? 2 : 1; Ns < N; Ns <<= 2) {
    int j = tid;
    int base = j & (Ns - 1);
    float2 t = g_tw[Ns + base];
    float2 w1 = make_float2(t.x, dirsign * t.y);
    float2 w2 = cmul(w1, w1);
    float2 w3 = cmul(w2, w1);
    float2 v0 = sbuf[cur][j];
    float2 v1 = cmul(sbuf[cur][j + N / 4], w1);
    float2 v2 = cmul(sbuf[cur][j + N / 2], w2);
    float2 v3 = cmul(sbuf[cur][j + 3 * (N / 4)], w3);
    float2 a0 = cadd(v0, v2), a1 = csub(v0, v2);
    float2 a2 = cadd(v1, v3), a3 = csub(v1, v3);
    float2 r1 = make_float2(-dirsign * a3.y, dirsign * a3.x);
    int idxD = ((j - base) << 2) + base;
    cur ^= 1;
    sbuf[cur][idxD]          = cadd(a0, a2);
    sbuf[cur][idxD + Ns]     = cadd(a1, r1);
    sbuf[cur][idxD + 2 * Ns] = csub(a0, a2);
    sbuf[cur][idxD + 3 * Ns] = csub(a1, r1);
    __syncthreads();
  }
  return cur;
}

// ---------------------------------------------------------------------------
// Batched row FFT (row-major in/out). Final 128^2 second pass.
// ---------------------------------------------------------------------------
template <int N, int LMODE, int SMODE>
__global__ void __launch_bounds__(N / 4)
fft_rows_k(const void* __restrict__ vin, void* __restrict__ vout,
           float dirsign, float scale) {
  constexpr int NT = N / 4;
  __shared__ __align__(16) float2 sbuf[2][N];
  const int tid = threadIdx.x;
  const int row = blockIdx.x;
  const int r = row & (N - 1);

  if (LMODE == 1) {
    const float2* in = (const float2*)vin;
#pragma unroll
    for (int i = tid; i < N; i += NT) {
      float2 v = in[(size_t)row * N + i];
      sbuf[0][i] = make_float2(v.x * scale, v.y * scale);
    }
  } else {
    const float2* in = (const float2*)vin;
    float pr = g_phi[phi_off(N) + r];
#pragma unroll
    for (int i = tid; i < N; i += NT) {
      float lm = pr * g_phi[phi_off(N) + i];
      float m = sqrtf(fmaxf(1.0f - lm * lm, 0.0f)) * scale;
      float2 v = in[(size_t)row * N + i];
      sbuf[0][i] = make_float2(v.x * m, v.y * m);
    }
  }
  __syncthreads();

  int cur = fft_core4<N>(sbuf, dirsign, tid, 0);

  if (SMODE == 0) {
    float2* outp = (float2*)vout;
#pragma unroll
    for (int i = tid; i < N; i += NT)
      outp[(size_t)row * N + i] = sbuf[cur][i];
  } else {
    float* outp = (float*)vout;
#pragma unroll
    for (int i = tid; i < N; i += NT)
      outp[(size_t)row * N + i] = sbuf[cur][i].x;
  }
}

// ---------------------------------------------------------------------------
// Paired row FFT with COLUMN-MAJOR output. LMODE 1: plain load.
// 2: load * Hm(r,i). 3: N=512 fold-combine * Hm.
// ---------------------------------------------------------------------------
template <int N, int LMODE>
__global__ void __launch_bounds__(N / 4)
fft_rows_cm_k(const float2* __restrict__ in, float2* __restrict__ outcm,
              float scale) {
  constexpr int NT = N / 4;
  __shared__ __align__(16) float2 sbuf[2][N];
  const int tid = threadIdx.x;
  const int img = blockIdx.y;
  const int b = blockIdx.x;                       // 0..N/2-1
  const int q = ((b & 7) << (ilog2c(N) - 4)) + (b >> 3);  // chunk = N/16
  float2 r0v[4], r1v[4];

#pragma unroll
  for (int half = 0; half < 2; ++half) {
    const int r = 2 * q + half;
    if constexpr (LMODE == 1) {
      const float2* rp = in + ((size_t)img * N + r) * N;
#pragma unroll
      for (int i = tid; i < N; i += NT) {
        float2 v = rp[i];
        sbuf[0][i] = make_float2(v.x * scale, v.y * scale);
      }
    } else if constexpr (LMODE == 2) {
      const float2* rp = in + ((size_t)img * N + r) * N;
      float pr = g_phi[phi_off(N) + r];
#pragma unroll
      for (int i = tid; i < N; i += NT) {
        float lm = pr * g_phi[phi_off(N) + i];
        float m = sqrtf(fmaxf(1.0f - lm * lm, 0.0f)) * scale;
        float2 v = rp[i];
        sbuf[0][i] = make_float2(v.x * m, v.y * m);
      }
    } else {  // LMODE 3, N == 512: fold-combine + Hm
      const float2* fb = in + (size_t)img * (513 * 512);
      const float2* fr0 = fb + (size_t)r * 512;
      const float2* fr1 = fb + (size_t)(512 - r) * 512;
      float pr = g_phi[phi_off(512) + r];
#pragma unroll
      for (int i = tid; i < N; i += NT) {
        float2 a = fr0[i], bb = fr1[(512 - i) & 511];
        float lm = pr * g_phi[phi_off(512) + i];
        float m = sqrtf(fmaxf(1.0f - lm * lm, 0.0f)) * scale;
        sbuf[0][i] = make_float2((a.x + bb.x) * m, (a.y - bb.y) * m);
      }
    }
    __syncthreads();

    int cur = fft_core4<N>(sbuf, 1.0f, tid, 0);

#pragma unroll
    for (int k = 0; k < 4; ++k) {
      int i = tid + k * NT;
      if (i < N) {
        float2 v = sbuf[cur][i];
        if (half == 0) r0v[k] = v; else r1v[k] = v;
      }
    }
    __syncthreads();  // next half's load overwrites sbuf[0]
  }

  float2* ob = outcm + (size_t)img * N * N + 2 * q;
#pragma unroll
  for (int k = 0; k < 4; ++k) {
    int i = tid + k * NT;
    if (i < N)
      *(float4*)&ob[(size_t)i * N] = make_float4(r0v[k].x, r0v[k].y, r1v[k].x, r1v[k].y);
  }
}

// ---------------------------------------------------------------------------
// First forward FFT on real input, TWO row-pairs per block, column-major
// half-spectrum output out[img][kx][y]. All 4 rows are loaded upfront as
// float4 (register prefetch): pair B's HBM latency hides under pair A's FFT.
// Stores: adjacent float4s (32 B granule) + XCD-chunk swizzle (proven WC).
// ---------------------------------------------------------------------------
template <int N, int PITCH>
__global__ void __launch_bounds__(N / 4)
rfft_pairs_cm2_k(const float* __restrict__ in, float2* __restrict__ out) {
  constexpr int NT = N / 4;
  __shared__ __align__(16) float2 sbuf[2][N];
  const int tid = threadIdx.x;
  const int img = blockIdx.y;
  const int b = blockIdx.x;                         // 0..N/4-1
  const int q = ((b & 7) << (ilog2c(N) - 5)) + (b >> 3);  // chunk = N/32
  const float* p = in + ((size_t)img * N + 4 * q) * N;

  // prefetch all 4 rows (2 pairs) — vectorized
  float4 a0 = *(const float4*)&p[4 * tid];
  float4 a1 = *(const float4*)&p[(size_t)N + 4 * tid];
  float4 b0 = *(const float4*)&p[(size_t)2 * N + 4 * tid];
  float4 b1 = *(const float4*)&p[(size_t)3 * N + 4 * tid];

  float2* ob = out + (size_t)img * ((size_t)PITCH * N) + 4 * q;
#pragma unroll 1
  for (int pair = 0; pair < 2; ++pair) {
    float4 ra = pair ? b0 : a0;
    float4 rb = pair ? b1 : a1;
    *(float4*)&sbuf[0][4 * tid]     = make_float4(ra.x, rb.x, ra.y, rb.y);
    *(float4*)&sbuf[0][4 * tid + 2] = make_float4(ra.z, rb.z, ra.w, rb.w);
    __syncthreads();

    int cur = fft_core4<N>(sbuf, -1.0f, tid, 0);

#pragma unroll
    for (int i = tid; i <= N / 2; i += NT) {
      float2 Z = sbuf[cur][i];
      float2 Zr = sbuf[cur][(N - i) & (N - 1)];
      float2 Zc = make_float2(Zr.x, -Zr.y);
      float2 o0 = make_float2(0.5f * (Z.x + Zc.x), 0.5f * (Z.y + Zc.y));
      float2 dd = make_float2(Z.x - Zc.x, Z.y - Zc.y);
      float2 o1 = make_float2(0.5f * dd.y, -0.5f * dd.x);
      *(float4*)&ob[(size_t)i * N + 2 * pair] = make_float4(o0.x, o0.y, o1.x, o1.y);
    }
    // next pair's sbuf[0] fill is safe (untangle reads sbuf[cur]=sbuf[1] for
    // N=1024); the fill->sync provides the write/read fence for stage 1.
  }
}

// ---------------------------------------------------------------------------
// Level-1 column pass, PAIRED + TRANSPOSED OUTPUT. Both columns' inputs are
// loaded upfront as float4 (register prefetch): kx1's HBM latency hides under
// kx0's two FFTs. Rest identical to the round-7-proven kernel.
// ---------------------------------------------------------------------------
template <int N, int PITCH>
__global__ void __launch_bounds__(N / 4)
fft_col_half_pair_k(const float2* __restrict__ in, float2* __restrict__ outT,
                    float2* __restrict__ foldb) {
  constexpr int NT = N / 4;
  constexpr int NH = N / 2;
  constexpr int NP = N / 4;           // number of kx pairs
  __shared__ __align__(16) float2 sbuf[2][N];
  const int tid = threadIdx.x;
  const int img = blockIdx.y;
  const int b = blockIdx.x;           // 0..NP (inclusive)
  const int t = (b < NP) ? (((b & 7) * (NP / 8)) + (b >> 3)) : NP;
  const float inv = 1.0f / (float)N;
  float2 k0[4], k1[4];

  const float2* rowp0 = in + ((size_t)img * PITCH + 2 * t) * N;
  const bool hasB = (2 * t + 1 <= NH);
  float4 A0 = *(const float4*)&rowp0[2 * tid];
  float4 A1 = *(const float4*)&rowp0[2 * tid + NH];
  float4 B0 = make_float4(0, 0, 0, 0), B1 = make_float4(0, 0, 0, 0);
  if (hasB) {
    B0 = *(const float4*)&rowp0[(size_t)N + 2 * tid];
    B1 = *(const float4*)&rowp0[(size_t)N + 2 * tid + NH];
  }

#pragma unroll 1
  for (int half = 0; half < 2; ++half) {
    const int kx = 2 * t + half;
    if (kx > NH) break;               // t==NP: only kx=N/2
    *(float4*)&sbuf[0][2 * tid]      = half ? B0 : A0;
    *(float4*)&sbuf[0][2 * tid + NH] = half ? B1 : A1;
    __syncthreads();

    int cur = fft_core4<N>(sbuf, -1.0f, tid, 0);

    const float pr = g_phi[phi_off(N) + kx];
    float2* fp = foldb + ((size_t)img * (NH + 1) + kx) * NH;
#pragma unroll
    for (int i = tid; i < NH; i += NT) {
      float2 vA = sbuf[cur][i];
      float2 vB = sbuf[cur][i + NH];
      float lmA = pr * g_phi[phi_off(N) + i];
      float lmB = pr * g_phi[phi_off(N) + i + NH];
      fp[i] = make_float2(0.25f * (vA.x * lmA + vB.x * lmB),
                          0.25f * (vA.y * lmA + vB.y * lmB));
      float hmA = sqrtf(fmaxf(1.0f - lmA * lmA, 0.0f)) * inv;
      float hmB = sqrtf(fmaxf(1.0f - lmB * lmB, 0.0f)) * inv;
      sbuf[cur][i]      = make_float2(vA.x * hmA, vA.y * hmA);
      sbuf[cur][i + NH] = make_float2(vB.x * hmB, vB.y * hmB);
    }
    __syncthreads();

    cur = fft_core4<N>(sbuf, 1.0f, tid, cur);

#pragma unroll
    for (int k = 0; k < 4; ++k) {
      int i = tid + k * NT;
      float2 v = sbuf[cur][i];
      if (half == 0) k0[k] = v; else k1[k] = v;
    }
    __syncthreads();                  // half-1 reload overwrites sbuf
  }

  if (t < NP) {
#pragma unroll
    for (int k = 0; k < 4; ++k) {
      int i = tid + k * NT;           // y
      *(float4*)&outT[((size_t)img * N + i) * PITCH + 2 * t] =
          make_float4(k0[k].x, k0[k].y, k1[k].x, k1[k].y);
    }
  } else {
#pragma unroll
    for (int k = 0; k < 4; ++k) {
      int i = tid + k * NT;
      outT[((size_t)img * N + i) * PITCH + NH] = k0[k];
    }
  }
}

// ---------------------------------------------------------------------------
// Level-3 spectrum from the fold buffer (spec2 never materialized).
// ---------------------------------------------------------------------------
__global__ void __launch_bounds__(256)
fold_spec3_k(const float2* __restrict__ fold, float2* __restrict__ spec3) {
  __shared__ float2 s2a[512], s2b[512];
  const int rp = blockIdx.x;        // 0..255
  const int img = blockIdx.y;       // 0..15
  const float2* fb = fold + (size_t)img * (513 * 512);
  const float2* fr0 = fb + (size_t)rp * 512;
  const float2* fr1 = fb + (size_t)(512 - rp) * 512;
  const float2* fr2 = fb + (size_t)(rp + 256) * 512;
  const float2* fr3 = fb + (size_t)(256 - rp) * 512;
  for (int c = threadIdx.x; c < 512; c += 256) {
    int mc = (512 - c) & 511;
    float2 a0 = fr0[c], b0 = fr1[mc];
    float2 a1 = fr2[c], b1 = fr3[mc];
    s2a[c] = make_float2(a0.x + b0.x, a0.y - b0.y);
    s2b[c] = make_float2(a1.x + b1.x, a1.y - b1.y);
  }
  __syncthreads();
  float pr0 = g_phi[phi_off(512) + rp], pr1 = g_phi[phi_off(512) + rp + 256];
  float2* sp3 = spec3 + ((size_t)img << 16) + ((size_t)rp << 8);
  {
    int c = threadIdx.x;  // 256 threads == 256 cols
    float pc0 = g_phi[phi_off(512) + c], pc1 = g_phi[phi_off(512) + c + 256];
    float2 v00 = s2a[c], v01 = s2a[c + 256], v10 = s2b[c], v11 = s2b[c + 256];
    float m00 = pr0 * pc0, m01 = pr0 * pc1, m10 = pr1 * pc0, m11 = pr1 * pc1;
    sp3[c] = make_float2(
        0.25f * (v00.x * m00 + v01.x * m01 + v10.x * m10 + v11.x * m11),
        0.25f * (v00.y * m00 + v01.y * m01 + v10.y * m10 + v11.y * m11));
  }
}

// ---------------------------------------------------------------------------
// Level-1 fused inverse row FFT + first DFB fan split, TWO q-units (4 rows)
// per block, sequential. q1's cache lines are touch-prefetched at block
// start so its loads L2-hit after q0's body.
// ---------------------------------------------------------------------------
template <int N, int PITCH>
__global__ void __launch_bounds__(N / 4)
ifft_fan_pair2_k(const float2* __restrict__ in, float* __restrict__ outb,
                 float scale, int halfT) {
  constexpr int NT = N / 4;
  constexpr int W2 = N / 2;
  __shared__ __align__(16) float2 sbuf[2][N];
  const int tid = threadIdx.x;
  const int img = blockIdx.x >> (ilog2c(N) - 2);   // N/4 units per image
  const int u = blockIdx.x & (N / 4 - 1);

  // touch-prefetch q1's two rows (one lane per 128B line)
  {
    const float2* tA = in + ((size_t)img * N + 4 * u + 2) * PITCH;
    const float2* tB = tA + PITCH;
    float pf = 0.0f;
    int i = tid * 16;
    if (i <= W2) pf = tA[i].x + tB[i].x;
    asm volatile("" :: "v"(pf));
  }

#pragma unroll 1
  for (int qq = 0; qq < 2; ++qq) {
    const int y0 = 4 * u + 2 * qq;
    const float2* inA = in + ((size_t)img * N + y0) * PITCH;
    const float2* inB = inA + PITCH;

#pragma unroll
    for (int i = tid; i <= W2; i += NT) {
      float2 a = inA[i], b = inB[i];
      sbuf[0][i] = make_float2((a.x - b.y) * scale, (a.y + b.x) * scale);
    }
#pragma unroll
    for (int i = tid; i < W2 - 1; i += NT) {
      int m = W2 - 1 - i;                  // source index: 511..1
      float2 a = inA[m], b = inB[m];
      sbuf[0][W2 + 1 + i] = make_float2((a.x + b.y) * scale, (b.x - a.y) * scale);
    }
    __syncthreads();

    int cur = fft_core4<N>(sbuf, 1.0f, tid, 0);

    float* scratch = (float*)sbuf[cur ^ 1];
    float* xe = scratch;            // W2 floats
    float* xo = scratch + W2;       // W2 floats
    float* db = scratch + 2 * W2;   // W2 floats
    const size_t rbase = ((size_t)img * N + y0) * W2;

    for (int sub = 0; sub < 2; ++sub) {
      const int par = sub;                 // y0 even, y1 odd
      const float sgn = par ? -1.0f : 1.0f;
#pragma unroll
      for (int i = tid; i < N; i += NT) {
        float v = par ? sbuf[cur][i].y : sbuf[cur][i].x;
        int ii = (i - par) & (N - 1);
        if (ii & 1) xo[ii >> 1] = v; else xe[ii >> 1] = v;
      }
      __syncthreads();

      float* outs = outb + rbase + (size_t)sub * W2;
      float* outd = outb + halfT + rbase + (size_t)sub * W2;
#pragma unroll 2
      for (int j = tid; j < W2; j += NT) {
        float acc = 0.0f;
#pragma unroll
        for (int k = 0; k < 12; k++)
          acc += c_pkva[k] * xe[(j - 6 + k + W2) & (W2 - 1)];
        float dv = sgn * (xo[j] - acc);
        db[j] = dv;
        outd[j] = dv;
      }
      __syncthreads();
#pragma unroll 2
      for (int j = tid; j < W2; j += NT) {
        float acc = 0.0f;
#pragma unroll
        for (int k = 0; k < 12; k++)
          acc += c_pkva[k] * db[(j - 6 + k + W2) & (W2 - 1)];
        outs[j] = sgn * xe[j] + 0.5f * acc;
      }
      __syncthreads();
    }
  }
}

// ---------------------------------------------------------------------------
// Fused: inverse row FFT + first DFB fan split (axis=-1). Levels 2/3.
// ---------------------------------------------------------------------------
template <int N>
__global__ void __launch_bounds__(N / 4)
ifft_fan_k(const float2* __restrict__ in, float* __restrict__ outb,
           float scale, int halfT) {
  constexpr int NT = N / 4;
  constexpr int W2 = N / 2;
  __shared__ __align__(16) float2 sbuf[2][N];
  const int tid = threadIdx.x;
  const int nr = blockIdx.x;
  const int r = nr & (N - 1);
  const int par = r & 1;
  const float sgn = par ? -1.0f : 1.0f;

#pragma unroll
  for (int i = tid; i < N; i += NT) {
    float2 v = in[(size_t)nr * N + i];
    sbuf[0][i] = make_float2(v.x * scale, v.y * scale);
  }
  __syncthreads();

  int cur = fft_core4<N>(sbuf, 1.0f, tid, 0);

  float* scratch = (float*)sbuf[cur ^ 1];
  float* xe = scratch;
  float* xo = scratch + W2;
  float* db = scratch + 2 * W2;
#pragma unroll
  for (int i = tid; i < N; i += NT) {
    float v = sbuf[cur][i].x;
    int ii = (i - par) & (N - 1);
    if (ii & 1) xo[ii >> 1] = v; else xe[ii >> 1] = v;
  }
  __syncthreads();

  float* outs = outb + (size_t)nr * W2;
  float* outd = outb + halfT + (size_t)nr * W2;
#pragma unroll 2
  for (int j = tid; j < W2; j += NT) {
    float acc = 0.0f;
#pragma unroll
    for (int k = 0; k < 12; k++)
      acc += c_pkva[k] * xe[(j - 6 + k + W2) & (W2 - 1)];
    float dv = sgn * (xo[j] - acc);
    db[j] = dv;
    outd[j] = dv;
  }
  __syncthreads();
#pragma unroll 2
  for (int j = tid; j < W2; j += NT) {
    float acc = 0.0f;
#pragma unroll
    for (int k = 0; k < 12; k++)
      acc += c_pkva[k] * db[(j - 6 + k + W2) & (W2 - 1)];
    outs[j] = sgn * xe[j] + 0.5f * acc;
  }
}

// Frequency-domain decimation by 2 with Lm mask (level 3->4), table-driven.
__global__ void alias_k(const float2* __restrict__ in, float2* __restrict__ out,
                        int N, int lgN2, int phiOff) {
  int idx = blockIdx.x * 256 + threadIdx.x;
  int N2 = N >> 1;
  int c = idx & (N2 - 1);
  int r = (idx >> lgN2) & (N2 - 1);
  int img = idx >> (2 * lgN2);
  float pr0 = g_phi[phiOff + r], pr1 = g_phi[phiOff + r + N2];
  float pc0 = g_phi[phiOff + c], pc1 = g_phi[phiOff + c + N2];
  size_t base = (size_t)img * N * N;
  float2 v00 = in[base + (size_t)r * N + c];
  float2 v01 = in[base + (size_t)r * N + c + N2];
  float2 v10 = in[base + (size_t)(r + N2) * N + c];
  float2 v11 = in[base + (size_t)(r + N2) * N + c + N2];
  float m00 = pr0 * pc0, m01 = pr0 * pc1, m10 = pr1 * pc0, m11 = pr1 * pc1;
  float2 o;
  o.x = 0.25f * (v00.x * m00 + v01.x * m01 + v10.x * m10 + v11.x * m11);
  o.y = 0.25f * (v00.y * m00 + v01.y * m01 + v10.y * m10 + v11.y * m11);
  out[((size_t)img << (2 * lgN2)) + ((size_t)r << lgN2) + c] = o;
}

// Standalone DFB fan split, axis=-1 (mid-pipeline; W <= 512 here).
// Loads vectorized: even/odd of a float2 (replaces stride-2 scalar gathers).
__global__ void __launch_bounds__(256)
fs_row_k(const float* __restrict__ x, float* __restrict__ outb,
         int lgH, int lgW, int halfT) {
  __shared__ float xe[512], xo[512], db[512];
  int H = 1 << lgH, W = 1 << lgW, W2 = W >> 1;
  int nr = blockIdx.x;
  int r = nr & (H - 1);
  int par = r & 1;
  float sgn = par ? -1.0f : 1.0f;
  const float2* x2 = (const float2*)(x + (size_t)nr * W);
  if (par) {
    for (int j = threadIdx.x; j < W2; j += 256) {
      float2 v0 = x2[j];
      float2 v1 = x2[(j + 1) & (W2 - 1)];
      xe[j] = sgn * v0.y;
      xo[j] = sgn * v1.x;
    }
  } else {
    for (int j = threadIdx.x; j < W2; j += 256) {
      float2 v0 = x2[j];
      xe[j] = sgn * v0.x;
      xo[j] = sgn * v0.y;
    }
  }
  __syncthreads();
  float* outs = outb + (size_t)nr * W2;
  float* outd = outb + halfT + (size_t)nr * W2;
  for (int j = threadIdx.x; j < W2; j += 256) {
    float acc = 0.0f;
#pragma unroll
    for (int k = 0; k < 12; k++)
      acc += c_pkva[k] * xe[(j - 6 + k + W2) & (W2 - 1)];
    float dv = xo[j] - acc;
    db[j] = dv;
    outd[j] = dv;
  }
  __syncthreads();
  for (int j = threadIdx.x; j < W2; j += 256) {
    float acc = 0.0f;
#pragma unroll
    for (int k = 0; k < 12; k++)
      acc += c_pkva[k] * db[(j - 6 + k + W2) & (W2 - 1)];
    outs[j] = xe[j] + 0.5f * acc;
  }
}

// ---------------------------------------------------------------------------
// FUSED column fan split (d AND s in one pass, input read once).
// ---------------------------------------------------------------------------
template <int TI, int TC>
__global__ void __launch_bounds__(256)
fs_col_fused_k(const float* __restrict__ x, float* __restrict__ outb,
               int lgH, int lgW, int halfT) {
  constexpr int RE = 2 * TI + 48;
  constexpr int DE = TI + 12;
  constexpr int NR = 256 / TC;
  __shared__ float raw[RE][TC];
  __shared__ float dvs[DE][TC];
  const int H = 1 << lgH, W = 1 << lgW;
  const int c0 = blockIdx.x * TC;
  const int i0 = blockIdx.y * TI;
  const int n = blockIdx.z;
  const int tc = threadIdx.x & (TC - 1);
  const int tr = threadIdx.x / TC;
  const float* xim = x + ((size_t)n << (lgH + lgW));
  const int rbase = 2 * i0 - 24;
#pragma unroll
  for (int r = tr; r < RE; r += NR) {
    int rr = (rbase + r) & (H - 1);
    raw[r][tc] = xim[((size_t)rr << lgW) + c0 + tc];
  }
  __syncthreads();
  const int par = tc & 1;
  for (int j = tr; j < DE; j += NR) {
    float acc = 0.0f;
#pragma unroll
    for (int k = 0; k < 12; k++)
      acc += c_pkva[k] * raw[2 * j + 2 * k + par][tc];
    dvs[j][tc] = raw[2 * j + 13 + par][tc] - acc;
  }
  __syncthreads();
  const float sgn = par ? -1.0f : 1.0f;
  float* outs = outb + (((size_t)n << (lgH - 1)) << lgW);
  float* outd = outs + halfT;
  for (int i = tr; i < TI; i += NR) {
    float acc = 0.0f;
#pragma unroll
    for (int k = 0; k < 12; k++)
      acc += c_pkva[k] * dvs[i + k][tc];
    float p0v = raw[2 * i + 24 + par][tc];
    size_t off = ((size_t)(i0 + i) << lgW) + c0 + tc;
    outd[off] = sgn * dvs[i + 6][tc];
    outs[off] = sgn * (p0v + 0.5f * acc);
  }
}

__global__ void fill_err_k(float* out) {
  out[threadIdx.x] = 1.0e9f;
}

// ---------------------------------------------------------------------------
extern "C" void kernel_launch(void* const* d_in, const int* in_sizes, int n_in,
                              void* d_out, int out_size, void* d_ws, size_t ws_size,
                              hipStream_t stream) {
  const float* x = (const float*)d_in[0];
  float* out = (float*)d_out;
  char* ws = (char*)d_ws;

  const size_t NEED = 220266496ull;
  if (ws_size < NEED) {
    fill_err_k<<<dim3(1), dim3(256), 0, stream>>>(out);
    return;
  }

  float2* bufA  = (float2*)(ws);                 // 16*1024*544*8 = 71303168
  float2* bufB  = (float2*)(ws + 71303168);      // 71303168
  float2* foldb = (float2*)(ws + 142606336);     // 16*513*512*8 = 33619968
  float2* spec3 = (float2*)(ws + 209780736);     // 8388608
  float2* spec4 = (float2*)(ws + 218169344);     // 2097152

  float* out0 = out;             // 262144
  float* out1 = out + 262144;    // 1048576
  float* out2 = out + 1310720;   // 4194304
  float* out3 = out + 5505024;   // 16777216

  phi_init_k<<<dim3(10), dim3(256), 0, stream>>>();

  // ---- Level 1 (half-spectrum in kx)
  rfft_pairs_cm2_k<1024, 544><<<dim3(256, 16), dim3(256), 0, stream>>>(x, bufB);
  // paired column pass writes ROW-MAJOR bufA[img][y][kx] directly (no transpose)
  fft_col_half_pair_k<1024, 544><<<dim3(257, 16), dim3(256), 0, stream>>>(bufB, bufA, foldb);
  fold_spec3_k<<<dim3(256, 16), dim3(256), 0, stream>>>(foldb, spec3);
  ifft_fan_pair2_k<1024, 544><<<dim3(4096), dim3(256), 0, stream>>>(bufA, (float*)bufB, 1.0f / 1024.0f, 8388608);
  // DFB n=4 remaining stages (fused column splits)
  fs_col_fused_k<64, 32><<<dim3(16, 8, 32), dim3(256), 0, stream>>>((float*)bufB, (float*)bufA, 10, 9, 8388608);
  fs_row_k<<<dim3(32768), dim3(256), 0, stream>>>((float*)bufA, (float*)bufB, 9, 9, 8388608);
  fs_col_fused_k<64, 32><<<dim3(8, 4, 128), dim3(256), 0, stream>>>((float*)bufB, out3, 9, 8, 8388608);

  // ---- Level 2: row FFT directly from fold buffer, column-major paired
  // output (spec2 and its transpose both eliminated)
  fft_rows_cm_k<512, 3><<<dim3(256, 16), dim3(128), 0, stream>>>(foldb, bufA, 1.0f / 512.0f);
  ifft_fan_k<512><<<dim3(8192), dim3(128), 0, stream>>>(bufA, (float*)bufB, 1.0f / 512.0f, 2097152);
  fs_col_fused_k<64, 32><<<dim3(8, 4, 32), dim3(256), 0, stream>>>((float*)bufB, (float*)bufA, 9, 8, 2097152);
  fs_row_k<<<dim3(16384), dim3(256), 0, stream>>>((float*)bufA, out2, 8, 8, 2097152);

  // ---- Level 3 (spec3 from fold_spec3_k)
  alias_k<<<dim3(1024), dim3(256), 0, stream>>>(spec3, spec4, 256, 7, phi_off(256));
  fft_rows_cm_k<256, 2><<<dim3(128, 16), dim3(64), 0, stream>>>(spec3, bufA, 1.0f / 256.0f);
  ifft_fan_k<256><<<dim3(4096), dim3(64), 0, stream>>>(bufA, (float*)bufB, 1.0f / 256.0f, 524288);
  fs_col_fused_k<64, 32><<<dim3(4, 2, 32), dim3(256), 0, stream>>>((float*)bufB, out1, 8, 7, 524288);

  // ---- Final lowpass: out0 = ifft2(X4^T) at 128^2 (cm first pass, no transpose)
  fft_rows_cm_k<128, 1><<<dim3(64, 16), dim3(32), 0, stream>>>(spec4, bufA, 1.0f / 128.0f);
  fft_rows_k<128, 1, 1><<<dim3(2048), dim3(32), 0, stream>>>((const void*)bufA, (void*)out0, 1.0f, 1.0f / 128.0f);
}

// Round 9
// 456.268 us; speedup vs baseline: 1.0906x; 1.0906x over previous
//
#include <hip/hip_runtime.h>
#include <math.h>

#define PI_F 3.14159265358979323846f

__constant__ float c_pkva[12] = {
  -0.0144f, 0.0272f, -0.0526f, 0.0972f, -0.193f, 0.63f,
   0.63f, -0.193f, 0.0972f, -0.0526f, 0.0272f, -0.0144f
};

constexpr int ilog2c(int n) { int l = 0; while (n > 1) { n >>= 1; ++l; } return l; }

// Meyer phi lookup table: [0,1024) for N=1024, [1024,1536) N=512,
// [1536,1792) N=256, [1792,1920) N=128. Filled by phi_init_k each launch.
__device__ float g_phi[1920];
// Radix-4 twiddle table: g_tw[Ns+base] = (cos th, sin th), th = 2pi*base/(4Ns).
__device__ float2 g_tw[512];
constexpr int phi_off(int N) {
  return (N == 1024) ? 0 : (N == 512) ? 1024 : (N == 256) ? 1536 : 1792;
}

__device__ __forceinline__ float phi_dev(int k, int n) {
  int kk = (k < n - k) ? k : (n - k);
  float w = 2.0f * PI_F * (float)kk / (float)n;
  float s = (w - PI_F / 3.0f) * (3.0f / PI_F);
  s = fminf(fmaxf(s, 0.0f), 1.0f);
  float s2 = s * s;
  float beta = s2 * s2 * (35.0f - 84.0f * s + 70.0f * s2 - 20.0f * s2 * s);
  return __cosf(0.5f * PI_F * beta);
}

__global__ void phi_init_k() {
  int i = blockIdx.x * 256 + threadIdx.x;
  if (i < 1024)      g_phi[i] = phi_dev(i, 1024);
  else if (i < 1536) g_phi[i] = phi_dev(i - 1024, 512);
  else if (i < 1792) g_phi[i] = phi_dev(i - 1536, 256);
  else if (i < 1920) g_phi[i] = phi_dev(i - 1792, 128);
  else {
    int idx = i - 1920;
    if (idx >= 1 && idx < 512) {
      int l = 31 - __clz(idx);
      int Ns = 1 << l;
      float th = 2.0f * PI_F * (float)(idx - Ns) / (float)(4 * Ns);
      g_tw[idx] = make_float2(cosf(th), sinf(th));
    }
  }
}

__device__ __forceinline__ float2 cmul(float2 a, float2 b) {
  return make_float2(a.x * b.x - a.y * b.y, a.x * b.y + a.y * b.x);
}
__device__ __forceinline__ float2 cadd(float2 a, float2 b) { return make_float2(a.x + b.x, a.y + b.y); }
__device__ __forceinline__ float2 csub(float2 a, float2 b) { return make_float2(a.x - b.x, a.y - b.y); }

// ---------------------------------------------------------------------------
// In-LDS Stockham radix-4 FFT core (unpadded — proven). NT = N/4.
// ---------------------------------------------------------------------------
template <int N>
__device__ __forceinline__ int fft_core4(float2 (*sbuf)[N], float dirsign, int tid, int cur) {
  constexpr int LOG2 = ilog2c(N);
  constexpr int NT = N / 4;
  constexpr bool LEAD2 = (LOG2 & 1);
  if constexpr (LEAD2) {
#pragma unroll
    for (int j = tid; j < N / 2; j += NT) {
      float2 v0 = sbuf[cur][j], v1 = sbuf[cur][j + N / 2];
      float2 e = cadd(v0, v1), o = csub(v0, v1);
      *(float4*)&sbuf[cur ^ 1][2 * j] = make_float4(e.x, e.y, o.x, o.y);
    }
    cur ^= 1;
    __syncthreads();
  }
#pragma unroll
  for (int Ns = LEAD2 ? 2 : 1; Ns < N; Ns <<= 2) {
    int j = tid;
    int base = j & (Ns - 1);
    float2 t = g_tw[Ns + base];
    float2 w1 = make_float2(t.x, dirsign * t.y);
    float2 w2 = cmul(w1, w1);
    float2 w3 = cmul(w2, w1);
    float2 v0 = sbuf[cur][j];
    float2 v1 = cmul(sbuf[cur][j + N / 4], w1);
    float2 v2 = cmul(sbuf[cur][j + N / 2], w2);
    float2 v3 = cmul(sbuf[cur][j + 3 * (N / 4)], w3);
    float2 a0 = cadd(v0, v2), a1 = csub(v0, v2);
    float2 a2 = cadd(v1, v3), a3 = csub(v1, v3);
    float2 r1 = make_float2(-dirsign * a3.y, dirsign * a3.x);
    int idxD = ((j - base) << 2) + base;
    cur ^= 1;
    sbuf[cur][idxD]          = cadd(a0, a2);
    sbuf[cur][idxD + Ns]     = cadd(a1, r1);
    sbuf[cur][idxD + 2 * Ns] = csub(a0, a2);
    sbuf[cur][idxD + 3 * Ns] = csub(a1, r1);
    __syncthreads();
  }
  return cur;
}

// ---------------------------------------------------------------------------
// Batched row FFT (row-major in/out). Final 128^2 second pass.
// ---------------------------------------------------------------------------
template <int N, int LMODE, int SMODE>
__global__ void __launch_bounds__(N / 4)
fft_rows_k(const void* __restrict__ vin, void* __restrict__ vout,
           float dirsign, float scale) {
  constexpr int NT = N / 4;
  __shared__ __align__(16) float2 sbuf[2][N];
  const int tid = threadIdx.x;
  const int row = blockIdx.x;
  const int r = row & (N - 1);

  if (LMODE == 1) {
    const float2* in = (const float2*)vin;
#pragma unroll
    for (int i = tid; i < N; i += NT) {
      float2 v = in[(size_t)row * N + i];
      sbuf[0][i] = make_float2(v.x * scale, v.y * scale);
    }
  } else {
    const float2* in = (const float2*)vin;
    float pr = g_phi[phi_off(N) + r];
#pragma unroll
    for (int i = tid; i < N; i += NT) {
      float lm = pr * g_phi[phi_off(N) + i];
      float m = sqrtf(fmaxf(1.0f - lm * lm, 0.0f)) * scale;
      float2 v = in[(size_t)row * N + i];
      sbuf[0][i] = make_float2(v.x * m, v.y * m);
    }
  }
  __syncthreads();

  int cur = fft_core4<N>(sbuf, dirsign, tid, 0);

  if (SMODE == 0) {
    float2* outp = (float2*)vout;
#pragma unroll
    for (int i = tid; i < N; i += NT)
      outp[(size_t)row * N + i] = sbuf[cur][i];
  } else {
    float* outp = (float*)vout;
#pragma unroll
    for (int i = tid; i < N; i += NT)
      outp[(size_t)row * N + i] = sbuf[cur][i].x;
  }
}

// ---------------------------------------------------------------------------
// Paired row FFT with COLUMN-MAJOR output (full spectrum; final lowpass).
// ---------------------------------------------------------------------------
template <int N, int LMODE>
__global__ void __launch_bounds__(N / 4)
fft_rows_cm_k(const float2* __restrict__ in, float2* __restrict__ outcm,
              float scale) {
  constexpr int NT = N / 4;
  __shared__ __align__(16) float2 sbuf[2][N];
  const int tid = threadIdx.x;
  const int img = blockIdx.y;
  const int b = blockIdx.x;                       // 0..N/2-1
  const int q = ((b & 7) << (ilog2c(N) - 4)) + (b >> 3);  // chunk = N/16
  float2 r0v[4], r1v[4];

#pragma unroll
  for (int half = 0; half < 2; ++half) {
    const int r = 2 * q + half;
    if constexpr (LMODE == 1) {
      const float2* rp = in + ((size_t)img * N + r) * N;
#pragma unroll
      for (int i = tid; i < N; i += NT) {
        float2 v = rp[i];
        sbuf[0][i] = make_float2(v.x * scale, v.y * scale);
      }
    } else {
      const float2* rp = in + ((size_t)img * N + r) * N;
      float pr = g_phi[phi_off(N) + r];
#pragma unroll
      for (int i = tid; i < N; i += NT) {
        float lm = pr * g_phi[phi_off(N) + i];
        float m = sqrtf(fmaxf(1.0f - lm * lm, 0.0f)) * scale;
        float2 v = rp[i];
        sbuf[0][i] = make_float2(v.x * m, v.y * m);
      }
    }
    __syncthreads();

    int cur = fft_core4<N>(sbuf, 1.0f, tid, 0);

#pragma unroll
    for (int k = 0; k < 4; ++k) {
      int i = tid + k * NT;
      if (i < N) {
        float2 v = sbuf[cur][i];
        if (half == 0) r0v[k] = v; else r1v[k] = v;
      }
    }
    __syncthreads();  // next half's load overwrites sbuf[0]
  }

  float2* ob = outcm + (size_t)img * N * N + 2 * q;
#pragma unroll
  for (int k = 0; k < 4; ++k) {
    int i = tid + k * NT;
    if (i < N)
      *(float4*)&ob[(size_t)i * N] = make_float4(r0v[k].x, r0v[k].y, r1v[k].x, r1v[k].y);
  }
}

// ---------------------------------------------------------------------------
// HALF-SPECTRUM paired first pass for levels 2/3: the level-L image is real,
// so W[x][(N-r)%N] = conj(W[x][r]) after the inverse pass over c — only rows
// r in [0, N/2] are needed. Block (b,img): rows r=2t, 2t+1 sequentially
// (inverse FFT over c, LMODE mask applied at load), results parked in
// registers, stored as float4 pairs column-major [img][x][r] (pitch PITCH)
// with the proven XCD-chunk swizzle. b==N/4 handles the r=N/2 singleton.
// LMODE 2: load * Hm. LMODE 3: N=512 fold-combine * Hm (spec2 never built).
// ---------------------------------------------------------------------------
template <int N, int PITCH, int LMODE>
__global__ void __launch_bounds__(N / 4)
fft_rows_cm_half_k(const float2* __restrict__ in, float2* __restrict__ outcm,
                   float scale) {
  constexpr int NT = N / 4;
  constexpr int NP = N / 4;           // number of row pairs
  __shared__ __align__(16) float2 sbuf[2][N];
  const int tid = threadIdx.x;
  const int img = blockIdx.y;
  const int b = blockIdx.x;           // 0..NP inclusive
  const int t = (b < NP) ? (((b & 7) * (NP / 8)) + (b >> 3)) : NP;
  float2 r0v[4], r1v[4];

#pragma unroll 1
  for (int half = 0; half < 2; ++half) {
    const int r = 2 * t + half;
    if (r > N / 2) break;             // t==NP: only r=N/2
    if constexpr (LMODE == 2) {
      const float2* rp = in + ((size_t)img * N + r) * N;
      float pr = g_phi[phi_off(N) + r];
#pragma unroll
      for (int i = tid; i < N; i += NT) {
        float lm = pr * g_phi[phi_off(N) + i];
        float m = sqrtf(fmaxf(1.0f - lm * lm, 0.0f)) * scale;
        float2 v = rp[i];
        sbuf[0][i] = make_float2(v.x * m, v.y * m);
      }
    } else {  // LMODE 3, N == 512: fold-combine + Hm
      const float2* fb = in + (size_t)img * (513 * 512);
      const float2* fr0 = fb + (size_t)r * 512;
      const float2* fr1 = fb + (size_t)(512 - r) * 512;
      float pr = g_phi[phi_off(512) + r];
#pragma unroll
      for (int i = tid; i < N; i += NT) {
        float2 a = fr0[i], bb = fr1[(512 - i) & 511];
        float lm = pr * g_phi[phi_off(512) + i];
        float m = sqrtf(fmaxf(1.0f - lm * lm, 0.0f)) * scale;
        sbuf[0][i] = make_float2((a.x + bb.x) * m, (a.y - bb.y) * m);
      }
    }
    __syncthreads();

    int cur = fft_core4<N>(sbuf, 1.0f, tid, 0);

#pragma unroll
    for (int k = 0; k < 4; ++k) {
      int i = tid + k * NT;
      float2 v = sbuf[cur][i];
      if (half == 0) r0v[k] = v; else r1v[k] = v;
    }
    __syncthreads();  // next half's load overwrites sbuf[0]
  }

  if (t < NP) {
    float2* ob = outcm + (size_t)img * ((size_t)PITCH * N) + 2 * t;
#pragma unroll
    for (int k = 0; k < 4; ++k) {
      int i = tid + k * NT;           // x
      *(float4*)&ob[(size_t)i * PITCH] =
          make_float4(r0v[k].x, r0v[k].y, r1v[k].x, r1v[k].y);
    }
  } else {
    float2* ob = outcm + (size_t)img * ((size_t)PITCH * N) + N / 2;
#pragma unroll
    for (int k = 0; k < 4; ++k) {
      int i = tid + k * NT;
      ob[(size_t)i * PITCH] = r0v[k];
    }
  }
}

// ---------------------------------------------------------------------------
// First forward FFT on real input, COLUMN-MAJOR half-spectrum output:
// rows (2r, 2r+1) packed as one complex FFT, untangled via Hermitian
// symmetry, stored directly as out[img][kx][y] (no transpose needed).
// ---------------------------------------------------------------------------
template <int N, int PITCH>
__global__ void __launch_bounds__(N / 4)
rfft_pairs_cm_k(const float* __restrict__ in, float2* __restrict__ out) {
  constexpr int NT = N / 4;
  __shared__ __align__(16) float2 sbuf[2][N];
  const int tid = threadIdx.x;
  const int img = blockIdx.x >> (ilog2c(N) - 1);
  const int b = blockIdx.x & (N / 2 - 1);
  const int r = ((b & 7) << (ilog2c(N) - 4)) + (b >> 3);  // chunk = N/16
  const float* p0 = in + ((size_t)img * N + 2 * r) * N;
  const float* p1 = p0 + N;

#pragma unroll
  for (int i = tid; i < N; i += NT)
    sbuf[0][i] = make_float2(p0[i], p1[i]);
  __syncthreads();

  int cur = fft_core4<N>(sbuf, -1.0f, tid, 0);

  float2* ob = out + (size_t)img * ((size_t)PITCH * N) + 2 * r;
#pragma unroll
  for (int i = tid; i <= N / 2; i += NT) {
    float2 Z = sbuf[cur][i];
    float2 Zr = sbuf[cur][(N - i) & (N - 1)];
    float2 Zc = make_float2(Zr.x, -Zr.y);
    float2 o0 = make_float2(0.5f * (Z.x + Zc.x), 0.5f * (Z.y + Zc.y));
    float2 dd = make_float2(Z.x - Zc.x, Z.y - Zc.y);
    float2 o1 = make_float2(0.5f * dd.y, -0.5f * dd.x);
    *(float4*)&ob[(size_t)i * N] = make_float4(o0.x, o0.y, o1.x, o1.y);
  }
}

// ---------------------------------------------------------------------------
// Level-1 column pass, PAIRED + TRANSPOSED OUTPUT (round-7-proven form).
// ---------------------------------------------------------------------------
template <int N, int PITCH>
__global__ void __launch_bounds__(N / 4)
fft_col_half_pair_k(const float2* __restrict__ in, float2* __restrict__ outT,
                    float2* __restrict__ foldb) {
  constexpr int NT = N / 4;
  constexpr int NH = N / 2;
  constexpr int NP = N / 4;           // number of kx pairs
  __shared__ __align__(16) float2 sbuf[2][N];
  const int tid = threadIdx.x;
  const int img = blockIdx.y;
  const int b = blockIdx.x;           // 0..NP (inclusive)
  const int t = (b < NP) ? (((b & 7) * (NP / 8)) + (b >> 3)) : NP;
  const float inv = 1.0f / (float)N;
  float2 k0[4], k1[4];

#pragma unroll 1
  for (int half = 0; half < 2; ++half) {
    const int kx = 2 * t + half;
    if (kx > NH) break;               // t==NP: only kx=N/2
    const float2* rowp = in + ((size_t)img * PITCH + kx) * N;
#pragma unroll
    for (int i = tid; i < N; i += NT)
      sbuf[0][i] = rowp[i];
    __syncthreads();

    int cur = fft_core4<N>(sbuf, -1.0f, tid, 0);

    const float pr = g_phi[phi_off(N) + kx];
    float2* fp = foldb + ((size_t)img * (NH + 1) + kx) * NH;
#pragma unroll
    for (int i = tid; i < NH; i += NT) {
      float2 vA = sbuf[cur][i];
      float2 vB = sbuf[cur][i + NH];
      float lmA = pr * g_phi[phi_off(N) + i];
      float lmB = pr * g_phi[phi_off(N) + i + NH];
      fp[i] = make_float2(0.25f * (vA.x * lmA + vB.x * lmB),
                          0.25f * (vA.y * lmA + vB.y * lmB));
      float hmA = sqrtf(fmaxf(1.0f - lmA * lmA, 0.0f)) * inv;
      float hmB = sqrtf(fmaxf(1.0f - lmB * lmB, 0.0f)) * inv;
      sbuf[cur][i]      = make_float2(vA.x * hmA, vA.y * hmA);
      sbuf[cur][i + NH] = make_float2(vB.x * hmB, vB.y * hmB);
    }
    __syncthreads();

    cur = fft_core4<N>(sbuf, 1.0f, tid, cur);

#pragma unroll
    for (int k = 0; k < 4; ++k) {
      int i = tid + k * NT;
      float2 v = sbuf[cur][i];
      if (half == 0) k0[k] = v; else k1[k] = v;
    }
    __syncthreads();                  // half-1 reload overwrites sbuf
  }

  if (t < NP) {
#pragma unroll
    for (int k = 0; k < 4; ++k) {
      int i = tid + k * NT;           // y
      *(float4*)&outT[((size_t)img * N + i) * PITCH + 2 * t] =
          make_float4(k0[k].x, k0[k].y, k1[k].x, k1[k].y);
    }
  } else {
#pragma unroll
    for (int k = 0; k < 4; ++k) {
      int i = tid + k * NT;
      outT[((size_t)img * N + i) * PITCH + NH] = k0[k];
    }
  }
}

// ---------------------------------------------------------------------------
// Level-3 spectrum from the fold buffer (spec2 never materialized).
// ---------------------------------------------------------------------------
__global__ void __launch_bounds__(256)
fold_spec3_k(const float2* __restrict__ fold, float2* __restrict__ spec3) {
  __shared__ float2 s2a[512], s2b[512];
  const int rp = blockIdx.x;        // 0..255
  const int img = blockIdx.y;       // 0..15
  const float2* fb = fold + (size_t)img * (513 * 512);
  const float2* fr0 = fb + (size_t)rp * 512;
  const float2* fr1 = fb + (size_t)(512 - rp) * 512;
  const float2* fr2 = fb + (size_t)(rp + 256) * 512;
  const float2* fr3 = fb + (size_t)(256 - rp) * 512;
  for (int c = threadIdx.x; c < 512; c += 256) {
    int mc = (512 - c) & 511;
    float2 a0 = fr0[c], b0 = fr1[mc];
    float2 a1 = fr2[c], b1 = fr3[mc];
    s2a[c] = make_float2(a0.x + b0.x, a0.y - b0.y);
    s2b[c] = make_float2(a1.x + b1.x, a1.y - b1.y);
  }
  __syncthreads();
  float pr0 = g_phi[phi_off(512) + rp], pr1 = g_phi[phi_off(512) + rp + 256];
  float2* sp3 = spec3 + ((size_t)img << 16) + ((size_t)rp << 8);
  {
    int c = threadIdx.x;  // 256 threads == 256 cols
    float pc0 = g_phi[phi_off(512) + c], pc1 = g_phi[phi_off(512) + c + 256];
    float2 v00 = s2a[c], v01 = s2a[c + 256], v10 = s2b[c], v11 = s2b[c + 256];
    float m00 = pr0 * pc0, m01 = pr0 * pc1, m10 = pr1 * pc0, m11 = pr1 * pc1;
    sp3[c] = make_float2(
        0.25f * (v00.x * m00 + v01.x * m01 + v10.x * m10 + v11.x * m11),
        0.25f * (v00.y * m00 + v01.y * m01 + v10.y * m10 + v11.y * m11));
  }
}

// ---------------------------------------------------------------------------
// Fused inverse FFT + first DFB fan split, TWO ROWS PER BLOCK via Hermitian
// pairing over the FFT index. Used at level 1 (rows y over kx), and at
// levels 2/3 (rows x over ky-frequency r) — same symmetry, same template.
// ---------------------------------------------------------------------------
template <int N, int PITCH>
__global__ void __launch_bounds__(N / 4)
ifft_fan_pair_k(const float2* __restrict__ in, float* __restrict__ outb,
                float scale, int halfT) {
  constexpr int NT = N / 4;
  constexpr int W2 = N / 2;
  __shared__ __align__(16) float2 sbuf[2][N];
  const int tid = threadIdx.x;
  const int img = blockIdx.x >> (ilog2c(N) - 1);
  const int q = blockIdx.x & (N / 2 - 1);
  const int y0 = 2 * q;
  const float2* inA = in + ((size_t)img * N + y0) * PITCH;
  const float2* inB = inA + PITCH;

#pragma unroll
  for (int i = tid; i <= W2; i += NT) {
    float2 a = inA[i], b = inB[i];
    sbuf[0][i] = make_float2((a.x - b.y) * scale, (a.y + b.x) * scale);
  }
#pragma unroll
  for (int i = tid; i < W2 - 1; i += NT) {
    int m = W2 - 1 - i;                  // source index: W2-1..1
    float2 a = inA[m], b = inB[m];
    sbuf[0][W2 + 1 + i] = make_float2((a.x + b.y) * scale, (b.x - a.y) * scale);
  }
  __syncthreads();

  int cur = fft_core4<N>(sbuf, 1.0f, tid, 0);

  float* scratch = (float*)sbuf[cur ^ 1];
  float* xe = scratch;            // W2 floats
  float* xo = scratch + W2;       // W2 floats
  float* db = scratch + 2 * W2;   // W2 floats
  const size_t rbase = ((size_t)img * N + y0) * W2;

  for (int sub = 0; sub < 2; ++sub) {
    const int par = sub;                 // y0 even, y1 odd
    const float sgn = par ? -1.0f : 1.0f;
#pragma unroll
    for (int i = tid; i < N; i += NT) {
      float v = par ? sbuf[cur][i].y : sbuf[cur][i].x;
      int ii = (i - par) & (N - 1);
      if (ii & 1) xo[ii >> 1] = v; else xe[ii >> 1] = v;
    }
    __syncthreads();

    float* outs = outb + rbase + (size_t)sub * W2;
    float* outd = outb + halfT + rbase + (size_t)sub * W2;
#pragma unroll 2
    for (int j = tid; j < W2; j += NT) {
      float acc = 0.0f;
#pragma unroll
      for (int k = 0; k < 12; k++)
        acc += c_pkva[k] * xe[(j - 6 + k + W2) & (W2 - 1)];
      float dv = sgn * (xo[j] - acc);
      db[j] = dv;
      outd[j] = dv;
    }
    __syncthreads();
#pragma unroll 2
    for (int j = tid; j < W2; j += NT) {
      float acc = 0.0f;
#pragma unroll
      for (int k = 0; k < 12; k++)
        acc += c_pkva[k] * db[(j - 6 + k + W2) & (W2 - 1)];
      outs[j] = sgn * xe[j] + 0.5f * acc;
    }
    __syncthreads();
  }
}

// Frequency-domain decimation by 2 with Lm mask (level 3->4), table-driven.
__global__ void alias_k(const float2* __restrict__ in, float2* __restrict__ out,
                        int N, int lgN2, int phiOff) {
  int idx = blockIdx.x * 256 + threadIdx.x;
  int N2 = N >> 1;
  int c = idx & (N2 - 1);
  int r = (idx >> lgN2) & (N2 - 1);
  int img = idx >> (2 * lgN2);
  float pr0 = g_phi[phiOff + r], pr1 = g_phi[phiOff + r + N2];
  float pc0 = g_phi[phiOff + c], pc1 = g_phi[phiOff + c + N2];
  size_t base = (size_t)img * N * N;
  float2 v00 = in[base + (size_t)r * N + c];
  float2 v01 = in[base + (size_t)r * N + c + N2];
  float2 v10 = in[base + (size_t)(r + N2) * N + c];
  float2 v11 = in[base + (size_t)(r + N2) * N + c + N2];
  float m00 = pr0 * pc0, m01 = pr0 * pc1, m10 = pr1 * pc0, m11 = pr1 * pc1;
  float2 o;
  o.x = 0.25f * (v00.x * m00 + v01.x * m01 + v10.x * m10 + v11.x * m11);
  o.y = 0.25f * (v00.y * m00 + v01.y * m01 + v10.y * m10 + v11.y * m11);
  out[((size_t)img << (2 * lgN2)) + ((size_t)r << lgN2) + c] = o;
}

// Standalone DFB fan split, axis=-1 (mid-pipeline; W <= 512 here).
__global__ void __launch_bounds__(256)
fs_row_k(const float* __restrict__ x, float* __restrict__ outb,
         int lgH, int lgW, int halfT) {
  __shared__ float xe[512], xo[512], db[512];
  int H = 1 << lgH, W = 1 << lgW, W2 = W >> 1;
  int nr = blockIdx.x;
  int r = nr & (H - 1);
  int par = r & 1;
  float sgn = par ? -1.0f : 1.0f;
  const float* xrow = x + (size_t)nr * W;
  for (int j = threadIdx.x; j < W2; j += 256) {
    xe[j] = sgn * xrow[(2 * j + par) & (W - 1)];
    xo[j] = sgn * xrow[(2 * j + 1 + par) & (W - 1)];
  }
  __syncthreads();
  float* outs = outb + (size_t)nr * W2;
  float* outd = outb + halfT + (size_t)nr * W2;
  for (int j = threadIdx.x; j < W2; j += 256) {
    float acc = 0.0f;
#pragma unroll
    for (int k = 0; k < 12; k++)
      acc += c_pkva[k] * xe[(j - 6 + k + W2) & (W2 - 1)];
    float dv = xo[j] - acc;
    db[j] = dv;
    outd[j] = dv;
  }
  __syncthreads();
  for (int j = threadIdx.x; j < W2; j += 256) {
    float acc = 0.0f;
#pragma unroll
    for (int k = 0; k < 12; k++)
      acc += c_pkva[k] * db[(j - 6 + k + W2) & (W2 - 1)];
    outs[j] = xe[j] + 0.5f * acc;
  }
}

// ---------------------------------------------------------------------------
// FUSED column fan split (d AND s in one pass, input read once).
// ---------------------------------------------------------------------------
template <int TI, int TC>
__global__ void __launch_bounds__(256)
fs_col_fused_k(const float* __restrict__ x, float* __restrict__ outb,
               int lgH, int lgW, int halfT) {
  constexpr int RE = 2 * TI + 48;
  constexpr int DE = TI + 12;
  constexpr int NR = 256 / TC;
  __shared__ float raw[RE][TC];
  __shared__ float dvs[DE][TC];
  const int H = 1 << lgH, W = 1 << lgW;
  const int c0 = blockIdx.x * TC;
  const int i0 = blockIdx.y * TI;
  const int n = blockIdx.z;
  const int tc = threadIdx.x & (TC - 1);
  const int tr = threadIdx.x / TC;
  const float* xim = x + ((size_t)n << (lgH + lgW));
  const int rbase = 2 * i0 - 24;
#pragma unroll
  for (int r = tr; r < RE; r += NR) {
    int rr = (rbase + r) & (H - 1);
    raw[r][tc] = xim[((size_t)rr << lgW) + c0 + tc];
  }
  __syncthreads();
  const int par = tc & 1;
  for (int j = tr; j < DE; j += NR) {
    float acc = 0.0f;
#pragma unroll
    for (int k = 0; k < 12; k++)
      acc += c_pkva[k] * raw[2 * j + 2 * k + par][tc];
    dvs[j][tc] = raw[2 * j + 13 + par][tc] - acc;
  }
  __syncthreads();
  const float sgn = par ? -1.0f : 1.0f;
  float* outs = outb + (((size_t)n << (lgH - 1)) << lgW);
  float* outd = outs + halfT;
  for (int i = tr; i < TI; i += NR) {
    float acc = 0.0f;
#pragma unroll
    for (int k = 0; k < 12; k++)
      acc += c_pkva[k] * dvs[i + k][tc];
    float p0v = raw[2 * i + 24 + par][tc];
    size_t off = ((size_t)(i0 + i) << lgW) + c0 + tc;
    outd[off] = sgn * dvs[i + 6][tc];
    outs[off] = sgn * (p0v + 0.5f * acc);
  }
}

__global__ void fill_err_k(float* out) {
  out[threadIdx.x] = 1.0e9f;
}

// ---------------------------------------------------------------------------
extern "C" void kernel_launch(void* const* d_in, const int* in_sizes, int n_in,
                              void* d_out, int out_size, void* d_ws, size_t ws_size,
                              hipStream_t stream) {
  const float* x = (const float*)d_in[0];
  float* out = (float*)d_out;
  char* ws = (char*)d_ws;

  const size_t NEED = 220266496ull;
  if (ws_size < NEED) {
    fill_err_k<<<dim3(1), dim3(256), 0, stream>>>(out);
    return;
  }

  float2* bufA  = (float2*)(ws);                 // 16*1024*544*8 = 71303168
  float2* bufB  = (float2*)(ws + 71303168);      // 71303168
  float2* foldb = (float2*)(ws + 142606336);     // 16*513*512*8 = 33619968
  float2* spec3 = (float2*)(ws + 209780736);     // 8388608
  float2* spec4 = (float2*)(ws + 218169344);     // 2097152

  float* out0 = out;             // 262144
  float* out1 = out + 262144;    // 1048576
  float* out2 = out + 1310720;   // 4194304
  float* out3 = out + 5505024;   // 16777216

  phi_init_k<<<dim3(10), dim3(256), 0, stream>>>();

  // ---- Level 1 (half-spectrum in kx)
  rfft_pairs_cm_k<1024, 544><<<dim3(8192), dim3(256), 0, stream>>>(x, bufB);
  // paired column pass writes ROW-MAJOR bufA[img][y][kx] directly (no transpose)
  fft_col_half_pair_k<1024, 544><<<dim3(257, 16), dim3(256), 0, stream>>>(bufB, bufA, foldb);
  fold_spec3_k<<<dim3(256, 16), dim3(256), 0, stream>>>(foldb, spec3);
  ifft_fan_pair_k<1024, 544><<<dim3(8192), dim3(256), 0, stream>>>(bufA, (float*)bufB, 1.0f / 1024.0f, 8388608);
  // DFB n=4 remaining stages (fused column splits)
  fs_col_fused_k<64, 32><<<dim3(16, 8, 32), dim3(256), 0, stream>>>((float*)bufB, (float*)bufA, 10, 9, 8388608);
  fs_row_k<<<dim3(32768), dim3(256), 0, stream>>>((float*)bufA, (float*)bufB, 9, 9, 8388608);
  fs_col_fused_k<64, 32><<<dim3(8, 4, 128), dim3(256), 0, stream>>>((float*)bufB, out3, 9, 8, 8388608);

  // ---- Level 2: half-spectrum first pass (Hermitian over r) from fold
  // buffer; paired inverse+fan (reuses the level-1-proven template)
  fft_rows_cm_half_k<512, 272, 3><<<dim3(129, 16), dim3(128), 0, stream>>>(foldb, bufA, 1.0f / 512.0f);
  ifft_fan_pair_k<512, 272><<<dim3(4096), dim3(128), 0, stream>>>(bufA, (float*)bufB, 1.0f / 512.0f, 2097152);
  fs_col_fused_k<64, 32><<<dim3(8, 4, 32), dim3(256), 0, stream>>>((float*)bufB, (float*)bufA, 9, 8, 2097152);
  fs_row_k<<<dim3(16384), dim3(256), 0, stream>>>((float*)bufA, out2, 8, 8, 2097152);

  // ---- Level 3 (spec3 from fold_spec3_k), half-spectrum first pass
  alias_k<<<dim3(1024), dim3(256), 0, stream>>>(spec3, spec4, 256, 7, phi_off(256));
  fft_rows_cm_half_k<256, 144, 2><<<dim3(65, 16), dim3(64), 0, stream>>>(spec3, bufA, 1.0f / 256.0f);
  ifft_fan_pair_k<256, 144><<<dim3(2048), dim3(64), 0, stream>>>(bufA, (float*)bufB, 1.0f / 256.0f, 524288);
  fs_col_fused_k<64, 32><<<dim3(4, 2, 32), dim3(256), 0, stream>>>((float*)bufB, out1, 8, 7, 524288);

  // ---- Final lowpass: out0 = ifft2(X4^T) at 128^2 (cm first pass, no transpose)
  fft_rows_cm_k<128, 1><<<dim3(64, 16), dim3(32), 0, stream>>>(spec4, bufA, 1.0f / 128.0f);
  fft_rows_k<128, 1, 1><<<dim3(2048), dim3(32), 0, stream>>>((const void*)bufA, (void*)out0, 1.0f, 1.0f / 128.0f);
}

// Round 10
// 449.910 us; speedup vs baseline: 1.1060x; 1.0141x over previous
//
#include <hip/hip_runtime.h>
#include <math.h>

#define PI_F 3.14159265358979323846f

__constant__ float c_pkva[12] = {
  -0.0144f, 0.0272f, -0.0526f, 0.0972f, -0.193f, 0.63f,
   0.63f, -0.193f, 0.0972f, -0.0526f, 0.0272f, -0.0144f
};

constexpr int ilog2c(int n) { int l = 0; while (n > 1) { n >>= 1; ++l; } return l; }

// Meyer phi lookup table: [0,1024) for N=1024, [1024,1536) N=512,
// [1536,1792) N=256, [1792,1920) N=128. Filled by phi_init_k each launch.
__device__ float g_phi[1920];
// Radix-4 twiddle table: g_tw[Ns+base] = (cos th, sin th), th = 2pi*base/(4Ns).
__device__ float2 g_tw[512];
constexpr int phi_off(int N) {
  return (N == 1024) ? 0 : (N == 512) ? 1024 : (N == 256) ? 1536 : 1792;
}

__device__ __forceinline__ float phi_dev(int k, int n) {
  int kk = (k < n - k) ? k : (n - k);
  float w = 2.0f * PI_F * (float)kk / (float)n;
  float s = (w - PI_F / 3.0f) * (3.0f / PI_F);
  s = fminf(fmaxf(s, 0.0f), 1.0f);
  float s2 = s * s;
  float beta = s2 * s2 * (35.0f - 84.0f * s + 70.0f * s2 - 20.0f * s2 * s);
  return __cosf(0.5f * PI_F * beta);
}

__global__ void phi_init_k() {
  int i = blockIdx.x * 256 + threadIdx.x;
  if (i < 1024)      g_phi[i] = phi_dev(i, 1024);
  else if (i < 1536) g_phi[i] = phi_dev(i - 1024, 512);
  else if (i < 1792) g_phi[i] = phi_dev(i - 1536, 256);
  else if (i < 1920) g_phi[i] = phi_dev(i - 1792, 128);
  else {
    int idx = i - 1920;
    if (idx >= 1 && idx < 512) {
      int l = 31 - __clz(idx);
      int Ns = 1 << l;
      float th = 2.0f * PI_F * (float)(idx - Ns) / (float)(4 * Ns);
      g_tw[idx] = make_float2(cosf(th), sinf(th));
    }
  }
}

__device__ __forceinline__ float2 cmul(float2 a, float2 b) {
  return make_float2(a.x * b.x - a.y * b.y, a.x * b.y + a.y * b.x);
}
__device__ __forceinline__ float2 cadd(float2 a, float2 b) { return make_float2(a.x + b.x, a.y + b.y); }
__device__ __forceinline__ float2 csub(float2 a, float2 b) { return make_float2(a.x - b.x, a.y - b.y); }

// ---------------------------------------------------------------------------
// In-LDS Stockham radix-4 FFT core (unpadded — proven). NT = N/4.
// NOTE: __syncthreads() inside syncs the WHOLE block; when two column-groups
// run this concurrently (fft_col_half_par_k) both execute the identical
// stage sequence, so the barriers align.
// ---------------------------------------------------------------------------
template <int N>
__device__ __forceinline__ int fft_core4(float2 (*sbuf)[N], float dirsign, int tid, int cur) {
  constexpr int LOG2 = ilog2c(N);
  constexpr int NT = N / 4;
  constexpr bool LEAD2 = (LOG2 & 1);
  if constexpr (LEAD2) {
#pragma unroll
    for (int j = tid; j < N / 2; j += NT) {
      float2 v0 = sbuf[cur][j], v1 = sbuf[cur][j + N / 2];
      float2 e = cadd(v0, v1), o = csub(v0, v1);
      *(float4*)&sbuf[cur ^ 1][2 * j] = make_float4(e.x, e.y, o.x, o.y);
    }
    cur ^= 1;
    __syncthreads();
  }
#pragma unroll
  for (int Ns = LEAD2 ? 2 : 1; Ns < N; Ns <<= 2) {
    int j = tid;
    int base = j & (Ns - 1);
    float2 t = g_tw[Ns + base];
    float2 w1 = make_float2(t.x, dirsign * t.y);
    float2 w2 = cmul(w1, w1);
    float2 w3 = cmul(w2, w1);
    float2 v0 = sbuf[cur][j];
    float2 v1 = cmul(sbuf[cur][j + N / 4], w1);
    float2 v2 = cmul(sbuf[cur][j + N / 2], w2);
    float2 v3 = cmul(sbuf[cur][j + 3 * (N / 4)], w3);
    float2 a0 = cadd(v0, v2), a1 = csub(v0, v2);
    float2 a2 = cadd(v1, v3), a3 = csub(v1, v3);
    float2 r1 = make_float2(-dirsign * a3.y, dirsign * a3.x);
    int idxD = ((j - base) << 2) + base;
    cur ^= 1;
    sbuf[cur][idxD]          = cadd(a0, a2);
    sbuf[cur][idxD + Ns]     = cadd(a1, r1);
    sbuf[cur][idxD + 2 * Ns] = csub(a0, a2);
    sbuf[cur][idxD + 3 * Ns] = csub(a1, r1);
    __syncthreads();
  }
  return cur;
}

// ---------------------------------------------------------------------------
// Batched row FFT (row-major in/out). Final 128^2 second pass.
// ---------------------------------------------------------------------------
template <int N, int LMODE, int SMODE>
__global__ void __launch_bounds__(N / 4)
fft_rows_k(const void* __restrict__ vin, void* __restrict__ vout,
           float dirsign, float scale) {
  constexpr int NT = N / 4;
  __shared__ __align__(16) float2 sbuf[2][N];
  const int tid = threadIdx.x;
  const int row = blockIdx.x;
  const int r = row & (N - 1);

  if (LMODE == 1) {
    const float2* in = (const float2*)vin;
#pragma unroll
    for (int i = tid; i < N; i += NT) {
      float2 v = in[(size_t)row * N + i];
      sbuf[0][i] = make_float2(v.x * scale, v.y * scale);
    }
  } else {
    const float2* in = (const float2*)vin;
    float pr = g_phi[phi_off(N) + r];
#pragma unroll
    for (int i = tid; i < N; i += NT) {
      float lm = pr * g_phi[phi_off(N) + i];
      float m = sqrtf(fmaxf(1.0f - lm * lm, 0.0f)) * scale;
      float2 v = in[(size_t)row * N + i];
      sbuf[0][i] = make_float2(v.x * m, v.y * m);
    }
  }
  __syncthreads();

  int cur = fft_core4<N>(sbuf, dirsign, tid, 0);

  if (SMODE == 0) {
    float2* outp = (float2*)vout;
#pragma unroll
    for (int i = tid; i < N; i += NT)
      outp[(size_t)row * N + i] = sbuf[cur][i];
  } else {
    float* outp = (float*)vout;
#pragma unroll
    for (int i = tid; i < N; i += NT)
      outp[(size_t)row * N + i] = sbuf[cur][i].x;
  }
}

// ---------------------------------------------------------------------------
// Paired row FFT with COLUMN-MAJOR output (full spectrum; final lowpass).
// ---------------------------------------------------------------------------
template <int N, int LMODE>
__global__ void __launch_bounds__(N / 4)
fft_rows_cm_k(const float2* __restrict__ in, float2* __restrict__ outcm,
              float scale) {
  constexpr int NT = N / 4;
  __shared__ __align__(16) float2 sbuf[2][N];
  const int tid = threadIdx.x;
  const int img = blockIdx.y;
  const int b = blockIdx.x;                       // 0..N/2-1
  const int q = ((b & 7) << (ilog2c(N) - 4)) + (b >> 3);  // chunk = N/16
  float2 r0v[4], r1v[4];

#pragma unroll
  for (int half = 0; half < 2; ++half) {
    const int r = 2 * q + half;
    if constexpr (LMODE == 1) {
      const float2* rp = in + ((size_t)img * N + r) * N;
#pragma unroll
      for (int i = tid; i < N; i += NT) {
        float2 v = rp[i];
        sbuf[0][i] = make_float2(v.x * scale, v.y * scale);
      }
    } else {
      const float2* rp = in + ((size_t)img * N + r) * N;
      float pr = g_phi[phi_off(N) + r];
#pragma unroll
      for (int i = tid; i < N; i += NT) {
        float lm = pr * g_phi[phi_off(N) + i];
        float m = sqrtf(fmaxf(1.0f - lm * lm, 0.0f)) * scale;
        float2 v = rp[i];
        sbuf[0][i] = make_float2(v.x * m, v.y * m);
      }
    }
    __syncthreads();

    int cur = fft_core4<N>(sbuf, 1.0f, tid, 0);

#pragma unroll
    for (int k = 0; k < 4; ++k) {
      int i = tid + k * NT;
      if (i < N) {
        float2 v = sbuf[cur][i];
        if (half == 0) r0v[k] = v; else r1v[k] = v;
      }
    }
    __syncthreads();  // next half's load overwrites sbuf[0]
  }

  float2* ob = outcm + (size_t)img * N * N + 2 * q;
#pragma unroll
  for (int k = 0; k < 4; ++k) {
    int i = tid + k * NT;
    if (i < N)
      *(float4*)&ob[(size_t)i * N] = make_float4(r0v[k].x, r0v[k].y, r1v[k].x, r1v[k].y);
  }
}

// ---------------------------------------------------------------------------
// HALF-SPECTRUM paired first pass for levels 2/3 (round-9-proven).
// LMODE 2: load * Hm. LMODE 3: N=512 fold-combine * Hm (spec2 never built).
// ---------------------------------------------------------------------------
template <int N, int PITCH, int LMODE>
__global__ void __launch_bounds__(N / 4)
fft_rows_cm_half_k(const float2* __restrict__ in, float2* __restrict__ outcm,
                   float scale) {
  constexpr int NT = N / 4;
  constexpr int NP = N / 4;           // number of row pairs
  __shared__ __align__(16) float2 sbuf[2][N];
  const int tid = threadIdx.x;
  const int img = blockIdx.y;
  const int b = blockIdx.x;           // 0..NP inclusive
  const int t = (b < NP) ? (((b & 7) * (NP / 8)) + (b >> 3)) : NP;
  float2 r0v[4], r1v[4];

#pragma unroll 1
  for (int half = 0; half < 2; ++half) {
    const int r = 2 * t + half;
    if (r > N / 2) break;             // t==NP: only r=N/2
    if constexpr (LMODE == 2) {
      const float2* rp = in + ((size_t)img * N + r) * N;
      float pr = g_phi[phi_off(N) + r];
#pragma unroll
      for (int i = tid; i < N; i += NT) {
        float lm = pr * g_phi[phi_off(N) + i];
        float m = sqrtf(fmaxf(1.0f - lm * lm, 0.0f)) * scale;
        float2 v = rp[i];
        sbuf[0][i] = make_float2(v.x * m, v.y * m);
      }
    } else {  // LMODE 3, N == 512: fold-combine + Hm
      const float2* fb = in + (size_t)img * (513 * 512);
      const float2* fr0 = fb + (size_t)r * 512;
      const float2* fr1 = fb + (size_t)(512 - r) * 512;
      float pr = g_phi[phi_off(512) + r];
#pragma unroll
      for (int i = tid; i < N; i += NT) {
        float2 a = fr0[i], bb = fr1[(512 - i) & 511];
        float lm = pr * g_phi[phi_off(512) + i];
        float m = sqrtf(fmaxf(1.0f - lm * lm, 0.0f)) * scale;
        sbuf[0][i] = make_float2((a.x + bb.x) * m, (a.y - bb.y) * m);
      }
    }
    __syncthreads();

    int cur = fft_core4<N>(sbuf, 1.0f, tid, 0);

#pragma unroll
    for (int k = 0; k < 4; ++k) {
      int i = tid + k * NT;
      float2 v = sbuf[cur][i];
      if (half == 0) r0v[k] = v; else r1v[k] = v;
    }
    __syncthreads();  // next half's load overwrites sbuf[0]
  }

  if (t < NP) {
    float2* ob = outcm + (size_t)img * ((size_t)PITCH * N) + 2 * t;
#pragma unroll
    for (int k = 0; k < 4; ++k) {
      int i = tid + k * NT;           // x
      *(float4*)&ob[(size_t)i * PITCH] =
          make_float4(r0v[k].x, r0v[k].y, r1v[k].x, r1v[k].y);
    }
  } else {
    float2* ob = outcm + (size_t)img * ((size_t)PITCH * N) + N / 2;
#pragma unroll
    for (int k = 0; k < 4; ++k) {
      int i = tid + k * NT;
      ob[(size_t)i * PITCH] = r0v[k];
    }
  }
}

// ---------------------------------------------------------------------------
// First forward FFT on real input, COLUMN-MAJOR half-spectrum output:
// rows (2r, 2r+1) packed as one complex FFT, untangled via Hermitian
// symmetry, stored directly as out[img][kx][y] (no transpose needed).
// ---------------------------------------------------------------------------
template <int N, int PITCH>
__global__ void __launch_bounds__(N / 4)
rfft_pairs_cm_k(const float* __restrict__ in, float2* __restrict__ out) {
  constexpr int NT = N / 4;
  __shared__ __align__(16) float2 sbuf[2][N];
  const int tid = threadIdx.x;
  const int img = blockIdx.x >> (ilog2c(N) - 1);
  const int b = blockIdx.x & (N / 2 - 1);
  const int r = ((b & 7) << (ilog2c(N) - 4)) + (b >> 3);  // chunk = N/16
  const float* p0 = in + ((size_t)img * N + 2 * r) * N;
  const float* p1 = p0 + N;

#pragma unroll
  for (int i = tid; i < N; i += NT)
    sbuf[0][i] = make_float2(p0[i], p1[i]);
  __syncthreads();

  int cur = fft_core4<N>(sbuf, -1.0f, tid, 0);

  float2* ob = out + (size_t)img * ((size_t)PITCH * N) + 2 * r;
#pragma unroll
  for (int i = tid; i <= N / 2; i += NT) {
    float2 Z = sbuf[cur][i];
    float2 Zr = sbuf[cur][(N - i) & (N - 1)];
    float2 Zc = make_float2(Zr.x, -Zr.y);
    float2 o0 = make_float2(0.5f * (Z.x + Zc.x), 0.5f * (Z.y + Zc.y));
    float2 dd = make_float2(Z.x - Zc.x, Z.y - Zc.y);
    float2 o1 = make_float2(0.5f * dd.y, -0.5f * dd.x);
    *(float4*)&ob[(size_t)i * N] = make_float4(o0.x, o0.y, o1.x, o1.y);
  }
}

// ---------------------------------------------------------------------------
// Level-1 column pass, CONCURRENT column pair + transposed float4 output.
// 512 threads: group 0 (tid 0-255) runs column kx=2t in sA, group 1 runs
// kx=2t+1 in sB, in lockstep (identical stage sequence -> aligned barriers
// inside fft_core4). Serial depth per block: 2 FFTs + 1 mask phase (was 4+2).
// Final store reads BOTH LDS buffers -> same float4 cm-store + XCD swizzle
// as the round-7/9-proven kernel (same addresses, same block timing).
// b==NP handles the kx=N/2 singleton (group 1 computes on clamped duplicate
// data, stores guarded off; barriers stay uniform).
// ---------------------------------------------------------------------------
template <int N, int PITCH>
__global__ void __launch_bounds__(N / 2)
fft_col_half_par_k(const float2* __restrict__ in, float2* __restrict__ outT,
                   float2* __restrict__ foldb) {
  constexpr int NT = N / 4;           // threads per column group
  constexpr int NH = N / 2;
  constexpr int NP = N / 4;           // number of kx pairs
  __shared__ __align__(16) float2 sA[2][N];
  __shared__ __align__(16) float2 sB[2][N];
  const int tid = threadIdx.x & (NT - 1);
  const int col = threadIdx.x / NT;   // 0 or 1
  const int img = blockIdx.y;
  const int b = blockIdx.x;           // 0..NP (inclusive)
  const int t = (b < NP) ? (((b & 7) * (NP / 8)) + (b >> 3)) : NP;
  const float inv = 1.0f / (float)N;
  const int kx = 2 * t + col;
  const bool active = (kx <= NH);
  const int kxc = active ? kx : NH;   // clamp for safe (duplicate) loads
  float2 (*sbuf)[N] = col ? sB : sA;

  const float2* rowp = in + ((size_t)img * PITCH + kxc) * N;
#pragma unroll
  for (int i = tid; i < N; i += NT)
    sbuf[0][i] = rowp[i];
  __syncthreads();

  int cur = fft_core4<N>(sbuf, -1.0f, tid, 0);

  const float pr = g_phi[phi_off(N) + kxc];
  float2* fp = foldb + ((size_t)img * (NH + 1) + kxc) * NH;
#pragma unroll
  for (int i = tid; i < NH; i += NT) {
    float2 vA = sbuf[cur][i];
    float2 vB = sbuf[cur][i + NH];
    float lmA = pr * g_phi[phi_off(N) + i];
    float lmB = pr * g_phi[phi_off(N) + i + NH];
    if (active)
      fp[i] = make_float2(0.25f * (vA.x * lmA + vB.x * lmB),
                          0.25f * (vA.y * lmA + vB.y * lmB));
    float hmA = sqrtf(fmaxf(1.0f - lmA * lmA, 0.0f)) * inv;
    float hmB = sqrtf(fmaxf(1.0f - lmB * lmB, 0.0f)) * inv;
    sbuf[cur][i]      = make_float2(vA.x * hmA, vA.y * hmA);
    sbuf[cur][i + NH] = make_float2(vB.x * hmB, vB.y * hmB);
  }
  __syncthreads();

  cur = fft_core4<N>(sbuf, 1.0f, tid, cur);
  // fft_core4's final stage ends with __syncthreads(): sA/sB finals visible.

  if (t < NP) {
#pragma unroll
    for (int y = threadIdx.x; y < N; y += N / 2) {
      float2 va = sA[cur][y], vb = sB[cur][y];
      *(float4*)&outT[((size_t)img * N + y) * PITCH + 2 * t] =
          make_float4(va.x, va.y, vb.x, vb.y);
    }
  } else {
#pragma unroll
    for (int y = threadIdx.x; y < N; y += N / 2)
      outT[((size_t)img * N + y) * PITCH + NH] = sA[cur][y];
  }
}

// ---------------------------------------------------------------------------
// Level-3 spectrum from the fold buffer (spec2 never materialized).
// ---------------------------------------------------------------------------
__global__ void __launch_bounds__(256)
fold_spec3_k(const float2* __restrict__ fold, float2* __restrict__ spec3) {
  __shared__ float2 s2a[512], s2b[512];
  const int rp = blockIdx.x;        // 0..255
  const int img = blockIdx.y;       // 0..15
  const float2* fb = fold + (size_t)img * (513 * 512);
  const float2* fr0 = fb + (size_t)rp * 512;
  const float2* fr1 = fb + (size_t)(512 - rp) * 512;
  const float2* fr2 = fb + (size_t)(rp + 256) * 512;
  const float2* fr3 = fb + (size_t)(256 - rp) * 512;
  for (int c = threadIdx.x; c < 512; c += 256) {
    int mc = (512 - c) & 511;
    float2 a0 = fr0[c], b0 = fr1[mc];
    float2 a1 = fr2[c], b1 = fr3[mc];
    s2a[c] = make_float2(a0.x + b0.x, a0.y - b0.y);
    s2b[c] = make_float2(a1.x + b1.x, a1.y - b1.y);
  }
  __syncthreads();
  float pr0 = g_phi[phi_off(512) + rp], pr1 = g_phi[phi_off(512) + rp + 256];
  float2* sp3 = spec3 + ((size_t)img << 16) + ((size_t)rp << 8);
  {
    int c = threadIdx.x;  // 256 threads == 256 cols
    float pc0 = g_phi[phi_off(512) + c], pc1 = g_phi[phi_off(512) + c + 256];
    float2 v00 = s2a[c], v01 = s2a[c + 256], v10 = s2b[c], v11 = s2b[c + 256];
    float m00 = pr0 * pc0, m01 = pr0 * pc1, m10 = pr1 * pc0, m11 = pr1 * pc1;
    sp3[c] = make_float2(
        0.25f * (v00.x * m00 + v01.x * m01 + v10.x * m10 + v11.x * m11),
        0.25f * (v00.y * m00 + v01.y * m01 + v10.y * m10 + v11.y * m11));
  }
}

// ---------------------------------------------------------------------------
// Fused inverse FFT + first DFB fan split, TWO ROWS PER BLOCK via Hermitian
// pairing over the FFT index. Level 1 (rows y over kx) and levels 2/3
// (rows x over ky-frequency r) — same symmetry, same template.
// ---------------------------------------------------------------------------
template <int N, int PITCH>
__global__ void __launch_bounds__(N / 4)
ifft_fan_pair_k(const float2* __restrict__ in, float* __restrict__ outb,
                float scale, int halfT) {
  constexpr int NT = N / 4;
  constexpr int W2 = N / 2;
  __shared__ __align__(16) float2 sbuf[2][N];
  const int tid = threadIdx.x;
  const int img = blockIdx.x >> (ilog2c(N) - 1);
  const int q = blockIdx.x & (N / 2 - 1);
  const int y0 = 2 * q;
  const float2* inA = in + ((size_t)img * N + y0) * PITCH;
  const float2* inB = inA + PITCH;

#pragma unroll
  for (int i = tid; i <= W2; i += NT) {
    float2 a = inA[i], b = inB[i];
    sbuf[0][i] = make_float2((a.x - b.y) * scale, (a.y + b.x) * scale);
  }
#pragma unroll
  for (int i = tid; i < W2 - 1; i += NT) {
    int m = W2 - 1 - i;                  // source index: W2-1..1
    float2 a = inA[m], b = inB[m];
    sbuf[0][W2 + 1 + i] = make_float2((a.x + b.y) * scale, (b.x - a.y) * scale);
  }
  __syncthreads();

  int cur = fft_core4<N>(sbuf, 1.0f, tid, 0);

  float* scratch = (float*)sbuf[cur ^ 1];
  float* xe = scratch;            // W2 floats
  float* xo = scratch + W2;       // W2 floats
  float* db = scratch + 2 * W2;   // W2 floats
  const size_t rbase = ((size_t)img * N + y0) * W2;

  for (int sub = 0; sub < 2; ++sub) {
    const int par = sub;                 // y0 even, y1 odd
    const float sgn = par ? -1.0f : 1.0f;
#pragma unroll
    for (int i = tid; i < N; i += NT) {
      float v = par ? sbuf[cur][i].y : sbuf[cur][i].x;
      int ii = (i - par) & (N - 1);
      if (ii & 1) xo[ii >> 1] = v; else xe[ii >> 1] = v;
    }
    __syncthreads();

    float* outs = outb + rbase + (size_t)sub * W2;
    float* outd = outb + halfT + rbase + (size_t)sub * W2;
#pragma unroll 2
    for (int j = tid; j < W2; j += NT) {
      float acc = 0.0f;
#pragma unroll
      for (int k = 0; k < 12; k++)
        acc += c_pkva[k] * xe[(j - 6 + k + W2) & (W2 - 1)];
      float dv = sgn * (xo[j] - acc);
      db[j] = dv;
      outd[j] = dv;
    }
    __syncthreads();
#pragma unroll 2
    for (int j = tid; j < W2; j += NT) {
      float acc = 0.0f;
#pragma unroll
      for (int k = 0; k < 12; k++)
        acc += c_pkva[k] * db[(j - 6 + k + W2) & (W2 - 1)];
      outs[j] = sgn * xe[j] + 0.5f * acc;
    }
    __syncthreads();
  }
}

// Frequency-domain decimation by 2 with Lm mask (level 3->4), table-driven.
__global__ void alias_k(const float2* __restrict__ in, float2* __restrict__ out,
                        int N, int lgN2, int phiOff) {
  int idx = blockIdx.x * 256 + threadIdx.x;
  int N2 = N >> 1;
  int c = idx & (N2 - 1);
  int r = (idx >> lgN2) & (N2 - 1);
  int img = idx >> (2 * lgN2);
  float pr0 = g_phi[phiOff + r], pr1 = g_phi[phiOff + r + N2];
  float pc0 = g_phi[phiOff + c], pc1 = g_phi[phiOff + c + N2];
  size_t base = (size_t)img * N * N;
  float2 v00 = in[base + (size_t)r * N + c];
  float2 v01 = in[base + (size_t)r * N + c + N2];
  float2 v10 = in[base + (size_t)(r + N2) * N + c];
  float2 v11 = in[base + (size_t)(r + N2) * N + c + N2];
  float m00 = pr0 * pc0, m01 = pr0 * pc1, m10 = pr1 * pc0, m11 = pr1 * pc1;
  float2 o;
  o.x = 0.25f * (v00.x * m00 + v01.x * m01 + v10.x * m10 + v11.x * m11);
  o.y = 0.25f * (v00.y * m00 + v01.y * m01 + v10.y * m10 + v11.y * m11);
  out[((size_t)img << (2 * lgN2)) + ((size_t)r << lgN2) + c] = o;
}

// Standalone DFB fan split, axis=-1 (mid-pipeline; W <= 512 here).
__global__ void __launch_bounds__(256)
fs_row_k(const float* __restrict__ x, float* __restrict__ outb,
         int lgH, int lgW, int halfT) {
  __shared__ float xe[512], xo[512], db[512];
  int H = 1 << lgH, W = 1 << lgW, W2 = W >> 1;
  int nr = blockIdx.x;
  int r = nr & (H - 1);
  int par = r & 1;
  float sgn = par ? -1.0f : 1.0f;
  const float* xrow = x + (size_t)nr * W;
  for (int j = threadIdx.x; j < W2; j += 256) {
    xe[j] = sgn * xrow[(2 * j + par) & (W - 1)];
    xo[j] = sgn * xrow[(2 * j + 1 + par) & (W - 1)];
  }
  __syncthreads();
  float* outs = outb + (size_t)nr * W2;
  float* outd = outb + halfT + (size_t)nr * W2;
  for (int j = threadIdx.x; j < W2; j += 256) {
    float acc = 0.0f;
#pragma unroll
    for (int k = 0; k < 12; k++)
      acc += c_pkva[k] * xe[(j - 6 + k + W2) & (W2 - 1)];
    float dv = xo[j] - acc;
    db[j] = dv;
    outd[j] = dv;
  }
  __syncthreads();
  for (int j = threadIdx.x; j < W2; j += 256) {
    float acc = 0.0f;
#pragma unroll
    for (int k = 0; k < 12; k++)
      acc += c_pkva[k] * db[(j - 6 + k + W2) & (W2 - 1)];
    outs[j] = xe[j] + 0.5f * acc;
  }
}

// ---------------------------------------------------------------------------
// FUSED column fan split (d AND s in one pass, input read once).
// ---------------------------------------------------------------------------
template <int TI, int TC>
__global__ void __launch_bounds__(256)
fs_col_fused_k(const float* __restrict__ x, float* __restrict__ outb,
               int lgH, int lgW, int halfT) {
  constexpr int RE = 2 * TI + 48;
  constexpr int DE = TI + 12;
  constexpr int NR = 256 / TC;
  __shared__ float raw[RE][TC];
  __shared__ float dvs[DE][TC];
  const int H = 1 << lgH, W = 1 << lgW;
  const int c0 = blockIdx.x * TC;
  const int i0 = blockIdx.y * TI;
  const int n = blockIdx.z;
  const int tc = threadIdx.x & (TC - 1);
  const int tr = threadIdx.x / TC;
  const float* xim = x + ((size_t)n << (lgH + lgW));
  const int rbase = 2 * i0 - 24;
#pragma unroll
  for (int r = tr; r < RE; r += NR) {
    int rr = (rbase + r) & (H - 1);
    raw[r][tc] = xim[((size_t)rr << lgW) + c0 + tc];
  }
  __syncthreads();
  const int par = tc & 1;
  for (int j = tr; j < DE; j += NR) {
    float acc = 0.0f;
#pragma unroll
    for (int k = 0; k < 12; k++)
      acc += c_pkva[k] * raw[2 * j + 2 * k + par][tc];
    dvs[j][tc] = raw[2 * j + 13 + par][tc] - acc;
  }
  __syncthreads();
  const float sgn = par ? -1.0f : 1.0f;
  float* outs = outb + (((size_t)n << (lgH - 1)) << lgW);
  float* outd = outs + halfT;
  for (int i = tr; i < TI; i += NR) {
    float acc = 0.0f;
#pragma unroll
    for (int k = 0; k < 12; k++)
      acc += c_pkva[k] * dvs[i + k][tc];
    float p0v = raw[2 * i + 24 + par][tc];
    size_t off = ((size_t)(i0 + i) << lgW) + c0 + tc;
    outd[off] = sgn * dvs[i + 6][tc];
    outs[off] = sgn * (p0v + 0.5f * acc);
  }
}

__global__ void fill_err_k(float* out) {
  out[threadIdx.x] = 1.0e9f;
}

// ---------------------------------------------------------------------------
extern "C" void kernel_launch(void* const* d_in, const int* in_sizes, int n_in,
                              void* d_out, int out_size, void* d_ws, size_t ws_size,
                              hipStream_t stream) {
  const float* x = (const float*)d_in[0];
  float* out = (float*)d_out;
  char* ws = (char*)d_ws;

  const size_t NEED = 220266496ull;
  if (ws_size < NEED) {
    fill_err_k<<<dim3(1), dim3(256), 0, stream>>>(out);
    return;
  }

  float2* bufA  = (float2*)(ws);                 // 16*1024*544*8 = 71303168
  float2* bufB  = (float2*)(ws + 71303168);      // 71303168
  float2* foldb = (float2*)(ws + 142606336);     // 16*513*512*8 = 33619968
  float2* spec3 = (float2*)(ws + 209780736);     // 8388608
  float2* spec4 = (float2*)(ws + 218169344);     // 2097152

  float* out0 = out;             // 262144
  float* out1 = out + 262144;    // 1048576
  float* out2 = out + 1310720;   // 4194304
  float* out3 = out + 5505024;   // 16777216

  phi_init_k<<<dim3(10), dim3(256), 0, stream>>>();

  // ---- Level 1 (half-spectrum in kx)
  rfft_pairs_cm_k<1024, 544><<<dim3(8192), dim3(256), 0, stream>>>(x, bufB);
  // concurrent column-pair pass writes ROW-MAJOR bufA[img][y][kx] directly
  fft_col_half_par_k<1024, 544><<<dim3(257, 16), dim3(512), 0, stream>>>(bufB, bufA, foldb);
  fold_spec3_k<<<dim3(256, 16), dim3(256), 0, stream>>>(foldb, spec3);
  ifft_fan_pair_k<1024, 544><<<dim3(8192), dim3(256), 0, stream>>>(bufA, (float*)bufB, 1.0f / 1024.0f, 8388608);
  // DFB n=4 remaining stages (fused column splits)
  fs_col_fused_k<64, 32><<<dim3(16, 8, 32), dim3(256), 0, stream>>>((float*)bufB, (float*)bufA, 10, 9, 8388608);
  fs_row_k<<<dim3(32768), dim3(256), 0, stream>>>((float*)bufA, (float*)bufB, 9, 9, 8388608);
  fs_col_fused_k<64, 32><<<dim3(8, 4, 128), dim3(256), 0, stream>>>((float*)bufB, out3, 9, 8, 8388608);

  // ---- Level 2: half-spectrum first pass (Hermitian over r) from fold
  // buffer; paired inverse+fan (level-1-proven template)
  fft_rows_cm_half_k<512, 272, 3><<<dim3(129, 16), dim3(128), 0, stream>>>(foldb, bufA, 1.0f / 512.0f);
  ifft_fan_pair_k<512, 272><<<dim3(4096), dim3(128), 0, stream>>>(bufA, (float*)bufB, 1.0f / 512.0f, 2097152);
  fs_col_fused_k<64, 32><<<dim3(8, 4, 32), dim3(256), 0, stream>>>((float*)bufB, (float*)bufA, 9, 8, 2097152);
  fs_row_k<<<dim3(16384), dim3(256), 0, stream>>>((float*)bufA, out2, 8, 8, 2097152);

  // ---- Level 3 (spec3 from fold_spec3_k), half-spectrum first pass
  alias_k<<<dim3(1024), dim3(256), 0, stream>>>(spec3, spec4, 256, 7, phi_off(256));
  fft_rows_cm_half_k<256, 144, 2><<<dim3(65, 16), dim3(64), 0, stream>>>(spec3, bufA, 1.0f / 256.0f);
  ifft_fan_pair_k<256, 144><<<dim3(2048), dim3(64), 0, stream>>>(bufA, (float*)bufB, 1.0f / 256.0f, 524288);
  fs_col_fused_k<64, 32><<<dim3(4, 2, 32), dim3(256), 0, stream>>>((float*)bufB, out1, 8, 7, 524288);

  // ---- Final lowpass: out0 = ifft2(X4^T) at 128^2 (cm first pass, no transpose)
  fft_rows_cm_k<128, 1><<<dim3(64, 16), dim3(32), 0, stream>>>(spec4, bufA, 1.0f / 128.0f);
  fft_rows_k<128, 1, 1><<<dim3(2048), dim3(32), 0, stream>>>((const void*)bufA, (void*)out0, 1.0f, 1.0f / 128.0f);
}

// Round 11
// 434.037 us; speedup vs baseline: 1.1465x; 1.0366x over previous
//
#include <hip/hip_runtime.h>
#include <math.h>

#define PI_F 3.14159265358979323846f

__constant__ float c_pkva[12] = {
  -0.0144f, 0.0272f, -0.0526f, 0.0972f, -0.193f, 0.63f,
   0.63f, -0.193f, 0.0972f, -0.0526f, 0.0272f, -0.0144f
};

constexpr int ilog2c(int n) { int l = 0; while (n > 1) { n >>= 1; ++l; } return l; }

// Meyer phi lookup table: [0,1024) for N=1024, [1024,1536) N=512,
// [1536,1792) N=256, [1792,1920) N=128. Filled by phi_init_k each launch.
__device__ float g_phi[1920];
// Radix-4 twiddle table: g_tw[Ns+base] = (cos th, sin th), th = 2pi*base/(4Ns).
__device__ float2 g_tw[512];
constexpr int phi_off(int N) {
  return (N == 1024) ? 0 : (N == 512) ? 1024 : (N == 256) ? 1536 : 1792;
}

__device__ __forceinline__ float phi_dev(int k, int n) {
  int kk = (k < n - k) ? k : (n - k);
  float w = 2.0f * PI_F * (float)kk / (float)n;
  float s = (w - PI_F / 3.0f) * (3.0f / PI_F);
  s = fminf(fmaxf(s, 0.0f), 1.0f);
  float s2 = s * s;
  float beta = s2 * s2 * (35.0f - 84.0f * s + 70.0f * s2 - 20.0f * s2 * s);
  return __cosf(0.5f * PI_F * beta);
}

__global__ void phi_init_k() {
  int i = blockIdx.x * 256 + threadIdx.x;
  if (i < 1024)      g_phi[i] = phi_dev(i, 1024);
  else if (i < 1536) g_phi[i] = phi_dev(i - 1024, 512);
  else if (i < 1792) g_phi[i] = phi_dev(i - 1536, 256);
  else if (i < 1920) g_phi[i] = phi_dev(i - 1792, 128);
  else {
    int idx = i - 1920;
    if (idx >= 1 && idx < 512) {
      int l = 31 - __clz(idx);
      int Ns = 1 << l;
      float th = 2.0f * PI_F * (float)(idx - Ns) / (float)(4 * Ns);
      g_tw[idx] = make_float2(cosf(th), sinf(th));
    }
  }
}

__device__ __forceinline__ float2 cmul(float2 a, float2 b) {
  return make_float2(a.x * b.x - a.y * b.y, a.x * b.y + a.y * b.x);
}
__device__ __forceinline__ float2 cadd(float2 a, float2 b) { return make_float2(a.x + b.x, a.y + b.y); }
__device__ __forceinline__ float2 csub(float2 a, float2 b) { return make_float2(a.x - b.x, a.y - b.y); }

// ---------------------------------------------------------------------------
// In-LDS Stockham radix-4 FFT core (unpadded — proven). NT = N/4.
// __syncthreads() inside syncs the WHOLE block; concurrent column-groups
// execute identical stage sequences, so barriers align (round-10 proven).
// ---------------------------------------------------------------------------
template <int N>
__device__ __forceinline__ int fft_core4(float2 (*sbuf)[N], float dirsign, int tid, int cur) {
  constexpr int LOG2 = ilog2c(N);
  constexpr int NT = N / 4;
  constexpr bool LEAD2 = (LOG2 & 1);
  if constexpr (LEAD2) {
#pragma unroll
    for (int j = tid; j < N / 2; j += NT) {
      float2 v0 = sbuf[cur][j], v1 = sbuf[cur][j + N / 2];
      float2 e = cadd(v0, v1), o = csub(v0, v1);
      *(float4*)&sbuf[cur ^ 1][2 * j] = make_float4(e.x, e.y, o.x, o.y);
    }
    cur ^= 1;
    __syncthreads();
  }
#pragma unroll
  for (int Ns = LEAD2 ? 2 : 1; Ns < N; Ns <<= 2) {
    int j = tid;
    int base = j & (Ns - 1);
    float2 t = g_tw[Ns + base];
    float2 w1 = make_float2(t.x, dirsign * t.y);
    float2 w2 = cmul(w1, w1);
    float2 w3 = cmul(w2, w1);
    float2 v0 = sbuf[cur][j];
    float2 v1 = cmul(sbuf[cur][j + N / 4], w1);
    float2 v2 = cmul(sbuf[cur][j + N / 2], w2);
    float2 v3 = cmul(sbuf[cur][j + 3 * (N / 4)], w3);
    float2 a0 = cadd(v0, v2), a1 = csub(v0, v2);
    float2 a2 = cadd(v1, v3), a3 = csub(v1, v3);
    float2 r1 = make_float2(-dirsign * a3.y, dirsign * a3.x);
    int idxD = ((j - base) << 2) + base;
    cur ^= 1;
    sbuf[cur][idxD]          = cadd(a0, a2);
    sbuf[cur][idxD + Ns]     = cadd(a1, r1);
    sbuf[cur][idxD + 2 * Ns] = csub(a0, a2);
    sbuf[cur][idxD + 3 * Ns] = csub(a1, r1);
    __syncthreads();
  }
  return cur;
}

// ---------------------------------------------------------------------------
// Batched row FFT (row-major in/out). Final 128^2 second pass.
// ---------------------------------------------------------------------------
template <int N, int LMODE, int SMODE>
__global__ void __launch_bounds__(N / 4)
fft_rows_k(const void* __restrict__ vin, void* __restrict__ vout,
           float dirsign, float scale) {
  constexpr int NT = N / 4;
  __shared__ __align__(16) float2 sbuf[2][N];
  const int tid = threadIdx.x;
  const int row = blockIdx.x;
  const int r = row & (N - 1);

  if (LMODE == 1) {
    const float2* in = (const float2*)vin;
#pragma unroll
    for (int i = tid; i < N; i += NT) {
      float2 v = in[(size_t)row * N + i];
      sbuf[0][i] = make_float2(v.x * scale, v.y * scale);
    }
  } else {
    const float2* in = (const float2*)vin;
    float pr = g_phi[phi_off(N) + r];
#pragma unroll
    for (int i = tid; i < N; i += NT) {
      float lm = pr * g_phi[phi_off(N) + i];
      float m = sqrtf(fmaxf(1.0f - lm * lm, 0.0f)) * scale;
      float2 v = in[(size_t)row * N + i];
      sbuf[0][i] = make_float2(v.x * m, v.y * m);
    }
  }
  __syncthreads();

  int cur = fft_core4<N>(sbuf, dirsign, tid, 0);

  if (SMODE == 0) {
    float2* outp = (float2*)vout;
#pragma unroll
    for (int i = tid; i < N; i += NT)
      outp[(size_t)row * N + i] = sbuf[cur][i];
  } else {
    float* outp = (float*)vout;
#pragma unroll
    for (int i = tid; i < N; i += NT)
      outp[(size_t)row * N + i] = sbuf[cur][i].x;
  }
}

// ---------------------------------------------------------------------------
// Paired row FFT with COLUMN-MAJOR output (full spectrum; final lowpass).
// ---------------------------------------------------------------------------
template <int N, int LMODE>
__global__ void __launch_bounds__(N / 4)
fft_rows_cm_k(const float2* __restrict__ in, float2* __restrict__ outcm,
              float scale) {
  constexpr int NT = N / 4;
  __shared__ __align__(16) float2 sbuf[2][N];
  const int tid = threadIdx.x;
  const int img = blockIdx.y;
  const int b = blockIdx.x;                       // 0..N/2-1
  const int q = ((b & 7) << (ilog2c(N) - 4)) + (b >> 3);  // chunk = N/16
  float2 r0v[4], r1v[4];

#pragma unroll
  for (int half = 0; half < 2; ++half) {
    const int r = 2 * q + half;
    if constexpr (LMODE == 1) {
      const float2* rp = in + ((size_t)img * N + r) * N;
#pragma unroll
      for (int i = tid; i < N; i += NT) {
        float2 v = rp[i];
        sbuf[0][i] = make_float2(v.x * scale, v.y * scale);
      }
    } else {
      const float2* rp = in + ((size_t)img * N + r) * N;
      float pr = g_phi[phi_off(N) + r];
#pragma unroll
      for (int i = tid; i < N; i += NT) {
        float lm = pr * g_phi[phi_off(N) + i];
        float m = sqrtf(fmaxf(1.0f - lm * lm, 0.0f)) * scale;
        float2 v = rp[i];
        sbuf[0][i] = make_float2(v.x * m, v.y * m);
      }
    }
    __syncthreads();

    int cur = fft_core4<N>(sbuf, 1.0f, tid, 0);

#pragma unroll
    for (int k = 0; k < 4; ++k) {
      int i = tid + k * NT;
      if (i < N) {
        float2 v = sbuf[cur][i];
        if (half == 0) r0v[k] = v; else r1v[k] = v;
      }
    }
    __syncthreads();  // next half's load overwrites sbuf[0]
  }

  float2* ob = outcm + (size_t)img * N * N + 2 * q;
#pragma unroll
  for (int k = 0; k < 4; ++k) {
    int i = tid + k * NT;
    if (i < N)
      *(float4*)&ob[(size_t)i * N] = make_float4(r0v[k].x, r0v[k].y, r1v[k].x, r1v[k].y);
  }
}

// ---------------------------------------------------------------------------
// HALF-SPECTRUM first pass for levels 2/3, CONCURRENT row pair (round-10
// pattern): 2*NT threads, group col runs row r=2t+col in its own LDS buffer
// in lockstep; joint float4 cm-store from both buffers (pitch PITCH) with
// the proven XCD-chunk swizzle. b==NP handles the r=N/2 singleton (group 1
// computes on clamped duplicate data, stores guarded; barriers uniform).
// LMODE 2: load * Hm. LMODE 3: N=512 fold-combine * Hm (spec2 never built).
// ---------------------------------------------------------------------------
template <int N, int PITCH, int LMODE>
__global__ void __launch_bounds__(N / 2)
fft_rows_cm_half_par_k(const float2* __restrict__ in, float2* __restrict__ outcm,
                       float scale) {
  constexpr int NT = N / 4;
  constexpr int NP = N / 4;           // number of row pairs
  __shared__ __align__(16) float2 sA[2][N];
  __shared__ __align__(16) float2 sB[2][N];
  const int tid = threadIdx.x & (NT - 1);
  const int col = threadIdx.x / NT;   // 0 or 1
  const int img = blockIdx.y;
  const int b = blockIdx.x;           // 0..NP inclusive
  const int t = (b < NP) ? (((b & 7) * (NP / 8)) + (b >> 3)) : NP;
  const int r0 = 2 * t + col;
  const bool active = (r0 <= N / 2);
  const int r = active ? r0 : N / 2;  // clamp: duplicate compute, store guarded
  float2 (*sbuf)[N] = col ? sB : sA;

  if constexpr (LMODE == 2) {
    const float2* rp = in + ((size_t)img * N + r) * N;
    float pr = g_phi[phi_off(N) + r];
#pragma unroll
    for (int i = tid; i < N; i += NT) {
      float lm = pr * g_phi[phi_off(N) + i];
      float m = sqrtf(fmaxf(1.0f - lm * lm, 0.0f)) * scale;
      float2 v = rp[i];
      sbuf[0][i] = make_float2(v.x * m, v.y * m);
    }
  } else {  // LMODE 3, N == 512: fold-combine + Hm
    const float2* fb = in + (size_t)img * (513 * 512);
    const float2* fr0 = fb + (size_t)r * 512;
    const float2* fr1 = fb + (size_t)(512 - r) * 512;
    float pr = g_phi[phi_off(512) + r];
#pragma unroll
    for (int i = tid; i < N; i += NT) {
      float2 a = fr0[i], bb = fr1[(512 - i) & 511];
      float lm = pr * g_phi[phi_off(512) + i];
      float m = sqrtf(fmaxf(1.0f - lm * lm, 0.0f)) * scale;
      sbuf[0][i] = make_float2((a.x + bb.x) * m, (a.y - bb.y) * m);
    }
  }
  __syncthreads();

  int cur = fft_core4<N>(sbuf, 1.0f, tid, 0);
  // fft_core4 ends with __syncthreads(): both sA and sB finals visible.

  if (t < NP) {
    float2* ob = outcm + (size_t)img * ((size_t)PITCH * N) + 2 * t;
#pragma unroll
    for (int i = threadIdx.x; i < N; i += N / 2) {
      float2 va = sA[cur][i], vb = sB[cur][i];
      *(float4*)&ob[(size_t)i * PITCH] = make_float4(va.x, va.y, vb.x, vb.y);
    }
  } else {
    float2* ob = outcm + (size_t)img * ((size_t)PITCH * N) + N / 2;
#pragma unroll
    for (int i = threadIdx.x; i < N; i += N / 2)
      ob[(size_t)i * PITCH] = sA[cur][i];
  }
}

// ---------------------------------------------------------------------------
// First forward FFT on real input, COLUMN-MAJOR half-spectrum output.
// VECTORIZED load phase: 2x float4 per thread (rows contiguous) covering
// i in [4t, 4t+4) — 4x fewer memory instructions in the serial prologue.
// Untangle + store path byte-identical to the round-5-proven kernel.
// ---------------------------------------------------------------------------
template <int N, int PITCH>
__global__ void __launch_bounds__(N / 4)
rfft_pairs_cm_k(const float* __restrict__ in, float2* __restrict__ out) {
  constexpr int NT = N / 4;
  __shared__ __align__(16) float2 sbuf[2][N];
  const int tid = threadIdx.x;
  const int img = blockIdx.x >> (ilog2c(N) - 1);
  const int b = blockIdx.x & (N / 2 - 1);
  const int r = ((b & 7) << (ilog2c(N) - 4)) + (b >> 3);  // chunk = N/16
  const float* p0 = in + ((size_t)img * N + 2 * r) * N;
  const float* p1 = p0 + N;

  {
    float4 f0 = *(const float4*)&p0[4 * tid];
    float4 f1 = *(const float4*)&p1[4 * tid];
    *(float4*)&sbuf[0][4 * tid]     = make_float4(f0.x, f1.x, f0.y, f1.y);
    *(float4*)&sbuf[0][4 * tid + 2] = make_float4(f0.z, f1.z, f0.w, f1.w);
  }
  __syncthreads();

  int cur = fft_core4<N>(sbuf, -1.0f, tid, 0);

  float2* ob = out + (size_t)img * ((size_t)PITCH * N) + 2 * r;
#pragma unroll
  for (int i = tid; i <= N / 2; i += NT) {
    float2 Z = sbuf[cur][i];
    float2 Zr = sbuf[cur][(N - i) & (N - 1)];
    float2 Zc = make_float2(Zr.x, -Zr.y);
    float2 o0 = make_float2(0.5f * (Z.x + Zc.x), 0.5f * (Z.y + Zc.y));
    float2 dd = make_float2(Z.x - Zc.x, Z.y - Zc.y);
    float2 o1 = make_float2(0.5f * dd.y, -0.5f * dd.x);
    *(float4*)&ob[(size_t)i * N] = make_float4(o0.x, o0.y, o1.x, o1.y);
  }
}

// ---------------------------------------------------------------------------
// Level-1 column pass, CONCURRENT column pair + transposed float4 output
// (round-10 proven).
// ---------------------------------------------------------------------------
template <int N, int PITCH>
__global__ void __launch_bounds__(N / 2)
fft_col_half_par_k(const float2* __restrict__ in, float2* __restrict__ outT,
                   float2* __restrict__ foldb) {
  constexpr int NT = N / 4;           // threads per column group
  constexpr int NH = N / 2;
  constexpr int NP = N / 4;           // number of kx pairs
  __shared__ __align__(16) float2 sA[2][N];
  __shared__ __align__(16) float2 sB[2][N];
  const int tid = threadIdx.x & (NT - 1);
  const int col = threadIdx.x / NT;   // 0 or 1
  const int img = blockIdx.y;
  const int b = blockIdx.x;           // 0..NP (inclusive)
  const int t = (b < NP) ? (((b & 7) * (NP / 8)) + (b >> 3)) : NP;
  const float inv = 1.0f / (float)N;
  const int kx = 2 * t + col;
  const bool active = (kx <= NH);
  const int kxc = active ? kx : NH;   // clamp for safe (duplicate) loads
  float2 (*sbuf)[N] = col ? sB : sA;

  const float2* rowp = in + ((size_t)img * PITCH + kxc) * N;
#pragma unroll
  for (int i = tid; i < N; i += NT)
    sbuf[0][i] = rowp[i];
  __syncthreads();

  int cur = fft_core4<N>(sbuf, -1.0f, tid, 0);

  const float pr = g_phi[phi_off(N) + kxc];
  float2* fp = foldb + ((size_t)img * (NH + 1) + kxc) * NH;
#pragma unroll
  for (int i = tid; i < NH; i += NT) {
    float2 vA = sbuf[cur][i];
    float2 vB = sbuf[cur][i + NH];
    float lmA = pr * g_phi[phi_off(N) + i];
    float lmB = pr * g_phi[phi_off(N) + i + NH];
    if (active)
      fp[i] = make_float2(0.25f * (vA.x * lmA + vB.x * lmB),
                          0.25f * (vA.y * lmA + vB.y * lmB));
    float hmA = sqrtf(fmaxf(1.0f - lmA * lmA, 0.0f)) * inv;
    float hmB = sqrtf(fmaxf(1.0f - lmB * lmB, 0.0f)) * inv;
    sbuf[cur][i]      = make_float2(vA.x * hmA, vA.y * hmA);
    sbuf[cur][i + NH] = make_float2(vB.x * hmB, vB.y * hmB);
  }
  __syncthreads();

  cur = fft_core4<N>(sbuf, 1.0f, tid, cur);
  // fft_core4's final stage ends with __syncthreads(): sA/sB finals visible.

  if (t < NP) {
#pragma unroll
    for (int y = threadIdx.x; y < N; y += N / 2) {
      float2 va = sA[cur][y], vb = sB[cur][y];
      *(float4*)&outT[((size_t)img * N + y) * PITCH + 2 * t] =
          make_float4(va.x, va.y, vb.x, vb.y);
    }
  } else {
#pragma unroll
    for (int y = threadIdx.x; y < N; y += N / 2)
      outT[((size_t)img * N + y) * PITCH + NH] = sA[cur][y];
  }
}

// ---------------------------------------------------------------------------
// Level-3 spectrum from the fold buffer (spec2 never materialized).
// ---------------------------------------------------------------------------
__global__ void __launch_bounds__(256)
fold_spec3_k(const float2* __restrict__ fold, float2* __restrict__ spec3) {
  __shared__ float2 s2a[512], s2b[512];
  const int rp = blockIdx.x;        // 0..255
  const int img = blockIdx.y;       // 0..15
  const float2* fb = fold + (size_t)img * (513 * 512);
  const float2* fr0 = fb + (size_t)rp * 512;
  const float2* fr1 = fb + (size_t)(512 - rp) * 512;
  const float2* fr2 = fb + (size_t)(rp + 256) * 512;
  const float2* fr3 = fb + (size_t)(256 - rp) * 512;
  for (int c = threadIdx.x; c < 512; c += 256) {
    int mc = (512 - c) & 511;
    float2 a0 = fr0[c], b0 = fr1[mc];
    float2 a1 = fr2[c], b1 = fr3[mc];
    s2a[c] = make_float2(a0.x + b0.x, a0.y - b0.y);
    s2b[c] = make_float2(a1.x + b1.x, a1.y - b1.y);
  }
  __syncthreads();
  float pr0 = g_phi[phi_off(512) + rp], pr1 = g_phi[phi_off(512) + rp + 256];
  float2* sp3 = spec3 + ((size_t)img << 16) + ((size_t)rp << 8);
  {
    int c = threadIdx.x;  // 256 threads == 256 cols
    float pc0 = g_phi[phi_off(512) + c], pc1 = g_phi[phi_off(512) + c + 256];
    float2 v00 = s2a[c], v01 = s2a[c + 256], v10 = s2b[c], v11 = s2b[c + 256];
    float m00 = pr0 * pc0, m01 = pr0 * pc1, m10 = pr1 * pc0, m11 = pr1 * pc1;
    sp3[c] = make_float2(
        0.25f * (v00.x * m00 + v01.x * m01 + v10.x * m10 + v11.x * m11),
        0.25f * (v00.y * m00 + v01.y * m01 + v10.y * m10 + v11.y * m11));
  }
}

// ---------------------------------------------------------------------------
// Fused inverse FFT + first DFB fan split, TWO ROWS PER BLOCK via Hermitian
// pairing over the FFT index. Level 1 (rows y over kx) and levels 2/3
// (rows x over ky-frequency r) — same symmetry, same template.
// ---------------------------------------------------------------------------
template <int N, int PITCH>
__global__ void __launch_bounds__(N / 4)
ifft_fan_pair_k(const float2* __restrict__ in, float* __restrict__ outb,
                float scale, int halfT) {
  constexpr int NT = N / 4;
  constexpr int W2 = N / 2;
  __shared__ __align__(16) float2 sbuf[2][N];
  const int tid = threadIdx.x;
  const int img = blockIdx.x >> (ilog2c(N) - 1);
  const int q = blockIdx.x & (N / 2 - 1);
  const int y0 = 2 * q;
  const float2* inA = in + ((size_t)img * N + y0) * PITCH;
  const float2* inB = inA + PITCH;

#pragma unroll
  for (int i = tid; i <= W2; i += NT) {
    float2 a = inA[i], b = inB[i];
    sbuf[0][i] = make_float2((a.x - b.y) * scale, (a.y + b.x) * scale);
  }
#pragma unroll
  for (int i = tid; i < W2 - 1; i += NT) {
    int m = W2 - 1 - i;                  // source index: W2-1..1
    float2 a = inA[m], b = inB[m];
    sbuf[0][W2 + 1 + i] = make_float2((a.x + b.y) * scale, (b.x - a.y) * scale);
  }
  __syncthreads();

  int cur = fft_core4<N>(sbuf, 1.0f, tid, 0);

  float* scratch = (float*)sbuf[cur ^ 1];
  float* xe = scratch;            // W2 floats
  float* xo = scratch + W2;       // W2 floats
  float* db = scratch + 2 * W2;   // W2 floats
  const size_t rbase = ((size_t)img * N + y0) * W2;

  for (int sub = 0; sub < 2; ++sub) {
    const int par = sub;                 // y0 even, y1 odd
    const float sgn = par ? -1.0f : 1.0f;
#pragma unroll
    for (int i = tid; i < N; i += NT) {
      float v = par ? sbuf[cur][i].y : sbuf[cur][i].x;
      int ii = (i - par) & (N - 1);
      if (ii & 1) xo[ii >> 1] = v; else xe[ii >> 1] = v;
    }
    __syncthreads();

    float* outs = outb + rbase + (size_t)sub * W2;
    float* outd = outb + halfT + rbase + (size_t)sub * W2;
#pragma unroll 2
    for (int j = tid; j < W2; j += NT) {
      float acc = 0.0f;
#pragma unroll
      for (int k = 0; k < 12; k++)
        acc += c_pkva[k] * xe[(j - 6 + k + W2) & (W2 - 1)];
      float dv = sgn * (xo[j] - acc);
      db[j] = dv;
      outd[j] = dv;
    }
    __syncthreads();
#pragma unroll 2
    for (int j = tid; j < W2; j += NT) {
      float acc = 0.0f;
#pragma unroll
      for (int k = 0; k < 12; k++)
        acc += c_pkva[k] * db[(j - 6 + k + W2) & (W2 - 1)];
      outs[j] = sgn * xe[j] + 0.5f * acc;
    }
    __syncthreads();
  }
}

// Frequency-domain decimation by 2 with Lm mask (level 3->4), table-driven.
__global__ void alias_k(const float2* __restrict__ in, float2* __restrict__ out,
                        int N, int lgN2, int phiOff) {
  int idx = blockIdx.x * 256 + threadIdx.x;
  int N2 = N >> 1;
  int c = idx & (N2 - 1);
  int r = (idx >> lgN2) & (N2 - 1);
  int img = idx >> (2 * lgN2);
  float pr0 = g_phi[phiOff + r], pr1 = g_phi[phiOff + r + N2];
  float pc0 = g_phi[phiOff + c], pc1 = g_phi[phiOff + c + N2];
  size_t base = (size_t)img * N * N;
  float2 v00 = in[base + (size_t)r * N + c];
  float2 v01 = in[base + (size_t)r * N + c + N2];
  float2 v10 = in[base + (size_t)(r + N2) * N + c];
  float2 v11 = in[base + (size_t)(r + N2) * N + c + N2];
  float m00 = pr0 * pc0, m01 = pr0 * pc1, m10 = pr1 * pc0, m11 = pr1 * pc1;
  float2 o;
  o.x = 0.25f * (v00.x * m00 + v01.x * m01 + v10.x * m10 + v11.x * m11);
  o.y = 0.25f * (v00.y * m00 + v01.y * m01 + v10.y * m10 + v11.y * m11);
  out[((size_t)img << (2 * lgN2)) + ((size_t)r << lgN2) + c] = o;
}

// Standalone DFB fan split, axis=-1 (mid-pipeline; W <= 512 here).
__global__ void __launch_bounds__(256)
fs_row_k(const float* __restrict__ x, float* __restrict__ outb,
         int lgH, int lgW, int halfT) {
  __shared__ float xe[512], xo[512], db[512];
  int H = 1 << lgH, W = 1 << lgW, W2 = W >> 1;
  int nr = blockIdx.x;
  int r = nr & (H - 1);
  int par = r & 1;
  float sgn = par ? -1.0f : 1.0f;
  const float* xrow = x + (size_t)nr * W;
  for (int j = threadIdx.x; j < W2; j += 256) {
    xe[j] = sgn * xrow[(2 * j + par) & (W - 1)];
    xo[j] = sgn * xrow[(2 * j + 1 + par) & (W - 1)];
  }
  __syncthreads();
  float* outs = outb + (size_t)nr * W2;
  float* outd = outb + halfT + (size_t)nr * W2;
  for (int j = threadIdx.x; j < W2; j += 256) {
    float acc = 0.0f;
#pragma unroll
    for (int k = 0; k < 12; k++)
      acc += c_pkva[k] * xe[(j - 6 + k + W2) & (W2 - 1)];
    float dv = xo[j] - acc;
    db[j] = dv;
    outd[j] = dv;
  }
  __syncthreads();
  for (int j = threadIdx.x; j < W2; j += 256) {
    float acc = 0.0f;
#pragma unroll
    for (int k = 0; k < 12; k++)
      acc += c_pkva[k] * db[(j - 6 + k + W2) & (W2 - 1)];
    outs[j] = xe[j] + 0.5f * acc;
  }
}

// ---------------------------------------------------------------------------
// FUSED column fan split (d AND s in one pass, input read once).
// ---------------------------------------------------------------------------
template <int TI, int TC>
__global__ void __launch_bounds__(256)
fs_col_fused_k(const float* __restrict__ x, float* __restrict__ outb,
               int lgH, int lgW, int halfT) {
  constexpr int RE = 2 * TI + 48;
  constexpr int DE = TI + 12;
  constexpr int NR = 256 / TC;
  __shared__ float raw[RE][TC];
  __shared__ float dvs[DE][TC];
  const int H = 1 << lgH, W = 1 << lgW;
  const int c0 = blockIdx.x * TC;
  const int i0 = blockIdx.y * TI;
  const int n = blockIdx.z;
  const int tc = threadIdx.x & (TC - 1);
  const int tr = threadIdx.x / TC;
  const float* xim = x + ((size_t)n << (lgH + lgW));
  const int rbase = 2 * i0 - 24;
#pragma unroll
  for (int r = tr; r < RE; r += NR) {
    int rr = (rbase + r) & (H - 1);
    raw[r][tc] = xim[((size_t)rr << lgW) + c0 + tc];
  }
  __syncthreads();
  const int par = tc & 1;
  for (int j = tr; j < DE; j += NR) {
    float acc = 0.0f;
#pragma unroll
    for (int k = 0; k < 12; k++)
      acc += c_pkva[k] * raw[2 * j + 2 * k + par][tc];
    dvs[j][tc] = raw[2 * j + 13 + par][tc] - acc;
  }
  __syncthreads();
  const float sgn = par ? -1.0f : 1.0f;
  float* outs = outb + (((size_t)n << (lgH - 1)) << lgW);
  float* outd = outs + halfT;
  for (int i = tr; i < TI; i += NR) {
    float acc = 0.0f;
#pragma unroll
    for (int k = 0; k < 12; k++)
      acc += c_pkva[k] * dvs[i + k][tc];
    float p0v = raw[2 * i + 24 + par][tc];
    size_t off = ((size_t)(i0 + i) << lgW) + c0 + tc;
    outd[off] = sgn * dvs[i + 6][tc];
    outs[off] = sgn * (p0v + 0.5f * acc);
  }
}

__global__ void fill_err_k(float* out) {
  out[threadIdx.x] = 1.0e9f;
}

// ---------------------------------------------------------------------------
extern "C" void kernel_launch(void* const* d_in, const int* in_sizes, int n_in,
                              void* d_out, int out_size, void* d_ws, size_t ws_size,
                              hipStream_t stream) {
  const float* x = (const float*)d_in[0];
  float* out = (float*)d_out;
  char* ws = (char*)d_ws;

  const size_t NEED = 220266496ull;
  if (ws_size < NEED) {
    fill_err_k<<<dim3(1), dim3(256), 0, stream>>>(out);
    return;
  }

  float2* bufA  = (float2*)(ws);                 // 16*1024*544*8 = 71303168
  float2* bufB  = (float2*)(ws + 71303168);      // 71303168
  float2* foldb = (float2*)(ws + 142606336);     // 16*513*512*8 = 33619968
  float2* spec3 = (float2*)(ws + 209780736);     // 8388608
  float2* spec4 = (float2*)(ws + 218169344);     // 2097152

  float* out0 = out;             // 262144
  float* out1 = out + 262144;    // 1048576
  float* out2 = out + 1310720;   // 4194304
  float* out3 = out + 5505024;   // 16777216

  phi_init_k<<<dim3(10), dim3(256), 0, stream>>>();

  // ---- Level 1 (half-spectrum in kx)
  rfft_pairs_cm_k<1024, 544><<<dim3(8192), dim3(256), 0, stream>>>(x, bufB);
  // concurrent column-pair pass writes ROW-MAJOR bufA[img][y][kx] directly
  fft_col_half_par_k<1024, 544><<<dim3(257, 16), dim3(512), 0, stream>>>(bufB, bufA, foldb);
  fold_spec3_k<<<dim3(256, 16), dim3(256), 0, stream>>>(foldb, spec3);
  ifft_fan_pair_k<1024, 544><<<dim3(8192), dim3(256), 0, stream>>>(bufA, (float*)bufB, 1.0f / 1024.0f, 8388608);
  // DFB n=4 remaining stages (fused column splits)
  fs_col_fused_k<64, 32><<<dim3(16, 8, 32), dim3(256), 0, stream>>>((float*)bufB, (float*)bufA, 10, 9, 8388608);
  fs_row_k<<<dim3(32768), dim3(256), 0, stream>>>((float*)bufA, (float*)bufB, 9, 9, 8388608);
  fs_col_fused_k<64, 32><<<dim3(8, 4, 128), dim3(256), 0, stream>>>((float*)bufB, out3, 9, 8, 8388608);

  // ---- Level 2: concurrent half-spectrum first pass from fold buffer;
  // paired inverse+fan (level-1-proven template)
  fft_rows_cm_half_par_k<512, 272, 3><<<dim3(129, 16), dim3(256), 0, stream>>>(foldb, bufA, 1.0f / 512.0f);
  ifft_fan_pair_k<512, 272><<<dim3(4096), dim3(128), 0, stream>>>(bufA, (float*)bufB, 1.0f / 512.0f, 2097152);
  fs_col_fused_k<64, 32><<<dim3(8, 4, 32), dim3(256), 0, stream>>>((float*)bufB, (float*)bufA, 9, 8, 2097152);
  fs_row_k<<<dim3(16384), dim3(256), 0, stream>>>((float*)bufA, out2, 8, 8, 2097152);

  // ---- Level 3 (spec3 from fold_spec3_k), concurrent half-spectrum pass
  alias_k<<<dim3(1024), dim3(256), 0, stream>>>(spec3, spec4, 256, 7, phi_off(256));
  fft_rows_cm_half_par_k<256, 144, 2><<<dim3(65, 16), dim3(128), 0, stream>>>(spec3, bufA, 1.0f / 256.0f);
  ifft_fan_pair_k<256, 144><<<dim3(2048), dim3(64), 0, stream>>>(bufA, (float*)bufB, 1.0f / 256.0f, 524288);
  fs_col_fused_k<64, 32><<<dim3(4, 2, 32), dim3(256), 0, stream>>>((float*)bufB, out1, 8, 7, 524288);

  // ---- Final lowpass: out0 = ifft2(X4^T) at 128^2 (cm first pass, no transpose)
  fft_rows_cm_k<128, 1><<<dim3(64, 16), dim3(32), 0, stream>>>(spec4, bufA, 1.0f / 128.0f);
  fft_rows_k<128, 1, 1><<<dim3(2048), dim3(32), 0, stream>>>((const void*)bufA, (void*)out0, 1.0f, 1.0f / 128.0f);
}